// Round 1
// baseline (1148.766 us; speedup 1.0000x reference)
//
#include <hip/hip_runtime.h>
#include <math.h>

// Problem constants (fixed by reference setup_inputs)
#define NNODES 102400      // B*S*M = 64*32*50
#define NEDGES 3276800
#define FIN 256
#define DTOTC 97
#define KTOP 30
#define NSUB 2048          // B*S
#define MSZ 50

// ---------------- CSR build ----------------
__global__ void k_hist(const int* __restrict__ col, int* __restrict__ cnt) {
    int e = blockIdx.x * blockDim.x + threadIdx.x;
    if (e < NEDGES) atomicAdd(&cnt[col[e]], 1);
}

__global__ void k_scan1(const int* __restrict__ cnt, int* __restrict__ offs, int* __restrict__ aux) {
    __shared__ int s[256];
    int i = blockIdx.x * 256 + threadIdx.x;
    int v = (i < NNODES) ? cnt[i] : 0;
    s[threadIdx.x] = v;
    __syncthreads();
    for (int d = 1; d < 256; d <<= 1) {
        int t = (threadIdx.x >= d) ? s[threadIdx.x - d] : 0;
        __syncthreads();
        s[threadIdx.x] += t;
        __syncthreads();
    }
    if (i < NNODES) offs[i] = s[threadIdx.x] - v;   // exclusive within block
    if (threadIdx.x == 255) aux[blockIdx.x] = s[255];
}

__global__ void k_scan2(int* __restrict__ aux, int nb) {
    __shared__ int s[512];
    int t = threadIdx.x;
    int v = (t < nb) ? aux[t] : 0;
    s[t] = v;
    __syncthreads();
    for (int d = 1; d < 512; d <<= 1) {
        int x = (t >= d) ? s[t - d] : 0;
        __syncthreads();
        s[t] += x;
        __syncthreads();
    }
    if (t < nb) aux[t] = s[t] - v;                  // exclusive block offsets
}

__global__ void k_scan3(int* __restrict__ offs, const int* __restrict__ aux,
                        const int* __restrict__ cnt, float* __restrict__ dinv) {
    int i = blockIdx.x * 256 + threadIdx.x;
    if (i < NNODES) {
        offs[i] += aux[i >> 8];
        dinv[i] = 1.0f / sqrtf((float)(cnt[i] + 1));   // +1 self loop
    }
    if (i == 0) offs[NNODES] = NEDGES;
}

__global__ void k_scatter(const int* __restrict__ ei, const int* __restrict__ offs,
                          int* __restrict__ cursor, int* __restrict__ csr_row) {
    int e = blockIdx.x * blockDim.x + threadIdx.x;
    if (e < NEDGES) {
        int r = ei[e];               // row (source)
        int c = ei[NEDGES + e];      // col (dest)
        int p = offs[c] + atomicAdd(&cursor[c], 1);
        csr_row[p] = r;
    }
}

// ---------------- layer-0 GEMM: hs = (x @ W0) * dinv[row] ----------------
// block = 256 threads -> 32 rows x 32 cols, 4 rows/thread
__global__ __launch_bounds__(256) void k_gemm256(const float* __restrict__ x,
                                                 const float* __restrict__ W,
                                                 const float* __restrict__ dinv,
                                                 float* __restrict__ hs) {
    __shared__ float Xs[32 * 256];   // 32 KB
    __shared__ float Ws[256 * 32];   // 32 KB, [k][col]
    int tid = threadIdx.x;
    int row0 = blockIdx.x * 32;
    const float4* Wv = (const float4*)W;
    const float4* Xv = (const float4*)(x + (size_t)row0 * 256);
    float4* Wsv = (float4*)Ws;
    float4* Xsv = (float4*)Xs;
    for (int i = tid; i < 2048; i += 256) {
        Wsv[i] = Wv[i];
        Xsv[i] = Xv[i];
    }
    __syncthreads();
    int colid = tid & 31;
    int rs = tid >> 5;               // 8 row slots; rows rs, rs+8, rs+16, rs+24
    float acc0 = 0.f, acc1 = 0.f, acc2 = 0.f, acc3 = 0.f;
    for (int k = 0; k < 256; k += 4) {
        float4 x0 = *(const float4*)&Xs[(rs) * 256 + k];
        float4 x1 = *(const float4*)&Xs[(rs + 8) * 256 + k];
        float4 x2 = *(const float4*)&Xs[(rs + 16) * 256 + k];
        float4 x3 = *(const float4*)&Xs[(rs + 24) * 256 + k];
        float w0 = Ws[(k + 0) * 32 + colid];
        float w1 = Ws[(k + 1) * 32 + colid];
        float w2 = Ws[(k + 2) * 32 + colid];
        float w3 = Ws[(k + 3) * 32 + colid];
        acc0 += x0.x * w0 + x0.y * w1 + x0.z * w2 + x0.w * w3;
        acc1 += x1.x * w0 + x1.y * w1 + x1.z * w2 + x1.w * w3;
        acc2 += x2.x * w0 + x2.y * w1 + x2.z * w2 + x2.w * w3;
        acc3 += x3.x * w0 + x3.y * w1 + x3.z * w2 + x3.w * w3;
    }
    hs[(size_t)(row0 + rs) * 32 + colid]      = acc0 * dinv[row0 + rs];
    hs[(size_t)(row0 + rs + 8) * 32 + colid]  = acc1 * dinv[row0 + rs + 8];
    hs[(size_t)(row0 + rs + 16) * 32 + colid] = acc2 * dinv[row0 + rs + 16];
    hs[(size_t)(row0 + rs + 24) * 32 + colid] = acc3 * dinv[row0 + rs + 24];
}

// ---------------- 32x32 GEMM: hs = (h @ W) * dinv[row] ----------------
__global__ __launch_bounds__(256) void k_gemm32(const float* __restrict__ h,
                                                const float* __restrict__ W,
                                                const float* __restrict__ dinv,
                                                float* __restrict__ hs) {
    __shared__ float Hs[64 * 32];    // 8 KB
    __shared__ float Ws[32 * 32];    // 4 KB, [k][col]
    int tid = threadIdx.x;
    int row0 = blockIdx.x * 64;
    const float4* Hv = (const float4*)(h + (size_t)row0 * 32);
    float4* Hsv = (float4*)Hs;
    for (int i = tid; i < 512; i += 256) Hsv[i] = Hv[i];
    for (int i = tid; i < 1024; i += 256) Ws[i] = W[i];
    __syncthreads();
    int colid = tid & 31;
    int rs = tid >> 5;
    for (int j = 0; j < 8; ++j) {
        int rl = rs * 8 + j;         // 0..63
        float acc = 0.f;
#pragma unroll
        for (int k = 0; k < 32; ++k) acc += Hs[rl * 32 + k] * Ws[k * 32 + colid];
        hs[(size_t)(row0 + rl) * 32 + colid] = acc * dinv[row0 + rl];
    }
}

// ---------------- aggregation (32 ch): out = tanh(dinv[c]*(sum hs[r] + hs[c]) + b) ----------------
__global__ __launch_bounds__(256) void k_agg32(const float* __restrict__ hs,
                                               const int* __restrict__ offs,
                                               const int* __restrict__ csr_row,
                                               const float* __restrict__ dinv,
                                               const float* __restrict__ bias,
                                               float* __restrict__ h_out,
                                               float* __restrict__ cs, int col_base) {
    int node = blockIdx.x * 8 + (threadIdx.x >> 5);
    int ch = threadIdx.x & 31;
    if (node >= NNODES) return;
    float acc = hs[(size_t)node * 32 + ch];      // self-loop term (pre-scaled)
    int s = offs[node], e = offs[node + 1];
    for (int i = s; i < e; ++i) {
        int r = csr_row[i];
        acc += hs[(size_t)r * 32 + ch];
    }
    float v = tanhf(dinv[node] * acc + bias[ch]);
    h_out[(size_t)node * 32 + ch] = v;
    cs[(size_t)node * DTOTC + col_base + ch] = v;
}

// ---------------- layer-3 (32 -> 1) ----------------
__global__ void k_gemv1(const float* __restrict__ h, const float* __restrict__ W3,
                        const float* __restrict__ dinv, float* __restrict__ hs4) {
    int i = blockIdx.x * 256 + threadIdx.x;
    if (i >= NNODES) return;
    float acc = 0.f;
#pragma unroll
    for (int k = 0; k < 32; ++k) acc += h[(size_t)i * 32 + k] * W3[k];
    hs4[i] = acc * dinv[i];
}

__global__ void k_agg1(const float* __restrict__ hs4, const int* __restrict__ offs,
                       const int* __restrict__ csr_row, const float* __restrict__ dinv,
                       const float* __restrict__ b3, float* __restrict__ cs) {
    int node = blockIdx.x * 256 + threadIdx.x;
    if (node >= NNODES) return;
    float acc = hs4[node];
    int s = offs[node], e = offs[node + 1];
    for (int i = s; i < e; ++i) acc += hs4[csr_row[i]];
    cs[(size_t)node * DTOTC + 96] = tanhf(dinv[node] * acc + b3[0]);
}

// ---------------- fused sortpool -> conv1 -> maxpool -> conv2 -> lin1 -> graph sum ----------------
__global__ __launch_bounds__(128) void k_sub(const float* __restrict__ cs,
                                             const float* __restrict__ c1w, const float* __restrict__ c1b,
                                             const float* __restrict__ c2w, const float* __restrict__ c2b,
                                             const float* __restrict__ l1w, const float* __restrict__ l1b,
                                             float* __restrict__ gsum) {
    __shared__ float csb[MSZ * DTOTC];     // 50*97
    __shared__ float c1ws[16 * DTOTC];
    __shared__ float c2ws[32 * 16 * 5];
    __shared__ float h1s[16 * 30];
    __shared__ float m1s[16 * 15];
    __shared__ float h2s[352];
    __shared__ int ord[KTOP];
    int tid = threadIdx.x;
    int sub = blockIdx.x;
    const float* src = cs + (size_t)sub * (MSZ * DTOTC);
    for (int i = tid; i < MSZ * DTOTC; i += 128) csb[i] = src[i];
    for (int i = tid; i < 16 * DTOTC; i += 128) c1ws[i] = c1w[i];
    for (int i = tid; i < 32 * 16 * 5; i += 128) c2ws[i] = c2w[i];
    __syncthreads();
    // stable descending rank by channel 96 (matches argsort(-v) stability)
    if (tid < MSZ) {
        float v = csb[tid * DTOTC + 96];
        int rank = 0;
        for (int j = 0; j < MSZ; ++j) {
            float vj = csb[j * DTOTC + 96];
            rank += (vj > v) || (vj == v && j < tid);
        }
        if (rank < KTOP) ord[rank] = tid;
    }
    __syncthreads();
    // conv1 (per-slot linear over 97) + relu -> h1[16][30]
    for (int p = tid; p < 16 * 30; p += 128) {
        int o = p / 30, k = p % 30;
        const float* xr = &csb[ord[k] * DTOTC];
        const float* wr = &c1ws[o * DTOTC];
        float acc = c1b[o];
        for (int d = 0; d < DTOTC; ++d) acc += xr[d] * wr[d];
        h1s[o * 30 + k] = fmaxf(acc, 0.f);
    }
    __syncthreads();
    // maxpool(2,2) -> m1[16][15]
    for (int p = tid; p < 16 * 15; p += 128) {
        int o = p / 15, j = p % 15;
        m1s[p] = fmaxf(h1s[o * 30 + 2 * j], h1s[o * 30 + 2 * j + 1]);
    }
    __syncthreads();
    // conv2 (k=5, valid) + relu -> h2[32][11], flattened channel-major
    for (int p = tid; p < 352; p += 128) {
        int o = p / 11, t = p % 11;
        float acc = c2b[o];
        for (int ic = 0; ic < 16; ++ic) {
#pragma unroll
            for (int j = 0; j < 5; ++j)
                acc += m1s[ic * 15 + t + j] * c2ws[(o * 16 + ic) * 5 + j];
        }
        h2s[p] = fmaxf(acc, 0.f);
    }
    __syncthreads();
    // lin1: h3[128] = h2 @ l1w + b ; accumulate into per-graph sum
    {
        int c = tid;   // 0..127
        float acc = l1b[c];
        for (int i = 0; i < 352; ++i) acc += h2s[i] * l1w[i * 128 + c];
        atomicAdd(&gsum[(sub >> 5) * 128 + c], acc);
    }
}

// ---------------- head: mean -> relu -> lin2 -> log_softmax ----------------
__global__ __launch_bounds__(128) void k_head(const float* __restrict__ gsum,
                                              const float* __restrict__ l2w,
                                              const float* __restrict__ l2b,
                                              float* __restrict__ out) {
    __shared__ float g[128];
    __shared__ float os[10];
    int b = blockIdx.x, tid = threadIdx.x;
    g[tid] = fmaxf(gsum[b * 128 + tid] * (1.0f / 32.0f), 0.f);
    __syncthreads();
    if (tid < 10) {
        float acc = l2b[tid];
        for (int k = 0; k < 128; ++k) acc += g[k] * l2w[k * 10 + tid];
        os[tid] = acc;
    }
    __syncthreads();
    if (tid == 0) {
        float m = os[0];
        for (int c = 1; c < 10; ++c) m = fmaxf(m, os[c]);
        float sum = 0.f;
        for (int c = 0; c < 10; ++c) sum += expf(os[c] - m);
        float l = m + logf(sum);
        for (int c = 0; c < 10; ++c) out[b * 10 + c] = os[c] - l;
    }
}

extern "C" void kernel_launch(void* const* d_in, const int* in_sizes, int n_in,
                              void* d_out, int out_size, void* d_ws, size_t ws_size,
                              hipStream_t stream) {
    const float* x   = (const float*)d_in[0];
    const int*   ei  = (const int*)d_in[1];
    const float* W0  = (const float*)d_in[2];
    const float* b0  = (const float*)d_in[3];
    const float* W1  = (const float*)d_in[4];
    const float* b1  = (const float*)d_in[5];
    const float* W2  = (const float*)d_in[6];
    const float* b2  = (const float*)d_in[7];
    const float* W3  = (const float*)d_in[8];
    const float* b3  = (const float*)d_in[9];
    const float* c1w = (const float*)d_in[10];
    const float* c1b = (const float*)d_in[11];
    const float* c2w = (const float*)d_in[12];
    const float* c2b = (const float*)d_in[13];
    const float* l1w = (const float*)d_in[14];
    const float* l1b = (const float*)d_in[15];
    const float* l2w = (const float*)d_in[16];
    const float* l2b = (const float*)d_in[17];
    float* out = (float*)d_out;

    char* ws = (char*)d_ws;
    size_t off = 0;
    auto alloc = [&](size_t bytes) {
        void* p = ws + off;
        off += (bytes + 255) & ~(size_t)255;
        return p;
    };
    int*   cnt     = (int*)alloc((NNODES + 1) * sizeof(int));
    int*   offs    = (int*)alloc((NNODES + 1) * sizeof(int));
    int*   cursor  = (int*)alloc((size_t)NNODES * sizeof(int));
    int*   aux     = (int*)alloc(512 * sizeof(int));
    float* dinv    = (float*)alloc((size_t)NNODES * sizeof(float));
    int*   csr_row = (int*)alloc((size_t)NEDGES * sizeof(int));
    float* bufA    = (float*)alloc((size_t)NNODES * 32 * sizeof(float));
    float* bufB    = (float*)alloc((size_t)NNODES * 32 * sizeof(float));
    float* cs      = (float*)alloc((size_t)NNODES * DTOTC * sizeof(float));
    float* hs4     = (float*)alloc((size_t)NNODES * sizeof(float));
    float* gsum    = (float*)alloc(64 * 128 * sizeof(float));

    hipMemsetAsync(cnt, 0, (NNODES + 1) * sizeof(int), stream);
    hipMemsetAsync(cursor, 0, (size_t)NNODES * sizeof(int), stream);
    hipMemsetAsync(gsum, 0, 64 * 128 * sizeof(float), stream);

    const int* col = ei + NEDGES;

    k_hist<<<(NEDGES + 255) / 256, 256, 0, stream>>>(col, cnt);
    k_scan1<<<(NNODES + 255) / 256, 256, 0, stream>>>(cnt, offs, aux);
    k_scan2<<<1, 512, 0, stream>>>(aux, (NNODES + 255) / 256);
    k_scan3<<<(NNODES + 255) / 256, 256, 0, stream>>>(offs, aux, cnt, dinv);
    k_scatter<<<(NEDGES + 255) / 256, 256, 0, stream>>>(ei, offs, cursor, csr_row);

    // layer 0: 256 -> 32
    k_gemm256<<<NNODES / 32, 256, 0, stream>>>(x, W0, dinv, bufA);
    k_agg32<<<NNODES / 8, 256, 0, stream>>>(bufA, offs, csr_row, dinv, b0, bufB, cs, 0);
    // layer 1: 32 -> 32
    k_gemm32<<<NNODES / 64, 256, 0, stream>>>(bufB, W1, dinv, bufA);
    k_agg32<<<NNODES / 8, 256, 0, stream>>>(bufA, offs, csr_row, dinv, b1, bufB, cs, 32);
    // layer 2: 32 -> 32
    k_gemm32<<<NNODES / 64, 256, 0, stream>>>(bufB, W2, dinv, bufA);
    k_agg32<<<NNODES / 8, 256, 0, stream>>>(bufA, offs, csr_row, dinv, b2, bufB, cs, 64);
    // layer 3: 32 -> 1
    k_gemv1<<<NNODES / 256, 256, 0, stream>>>(bufB, W3, dinv, hs4);
    k_agg1<<<NNODES / 256, 256, 0, stream>>>(hs4, offs, csr_row, dinv, b3, cs);

    // sortpool + conv stack + lin1 + per-graph sum
    k_sub<<<NSUB, 128, 0, stream>>>(cs, c1w, c1b, c2w, c2b, l1w, l1b, gsum);
    // mean -> relu -> lin2 -> log_softmax
    k_head<<<64, 128, 0, stream>>>(gsum, l2w, l2b, out);
}

// Round 2
// 1091.319 us; speedup vs baseline: 1.0526x; 1.0526x over previous
//
#include <hip/hip_runtime.h>
#include <math.h>

// Problem constants (fixed by reference setup_inputs)
#define NNODES 102400      // B*S*M = 64*32*50
#define NEDGES 3276800
#define FIN 256
#define DTOTC 97
#define KTOP 30
#define NSUB 2048          // B*S
#define MSZ 50
#define NBKT 1600          // dst-range buckets of 64 nodes each
#define BCAP 3584          // bucket staging cap (mean 2048, sigma ~45 -> 34 sigma)

// ---------------- CSR build: two-level counting sort ----------------
// Phase 0: bucket histogram (LDS-local then flush)
__global__ __launch_bounds__(256) void k_histB(const int* __restrict__ col, int* __restrict__ bcnt) {
    __shared__ int h[NBKT];
    int tid = threadIdx.x;
    for (int i = tid; i < NBKT; i += 256) h[i] = 0;
    __syncthreads();
    int e0 = blockIdx.x * 2048 + tid * 8;
    int4 c0 = *(const int4*)&col[e0];
    int4 c1 = *(const int4*)&col[e0 + 4];
    atomicAdd(&h[c0.x >> 6], 1);
    atomicAdd(&h[c0.y >> 6], 1);
    atomicAdd(&h[c0.z >> 6], 1);
    atomicAdd(&h[c0.w >> 6], 1);
    atomicAdd(&h[c1.x >> 6], 1);
    atomicAdd(&h[c1.y >> 6], 1);
    atomicAdd(&h[c1.z >> 6], 1);
    atomicAdd(&h[c1.w >> 6], 1);
    __syncthreads();
    for (int i = tid; i < NBKT; i += 256) {
        int v = h[i];
        if (v) atomicAdd(&bcnt[i], v);
    }
}

// Phase 1: exclusive scan of 1600 bucket counts (single block), init cursors + sentinels
__global__ __launch_bounds__(256) void k_scanB(const int* __restrict__ bcnt,
                                               int* __restrict__ bbase, int* __restrict__ bcur,
                                               int* __restrict__ offs) {
    __shared__ int s[256];
    int t = threadIdx.x;
    int lo = t * 7;
    int loc[7];
    int sum = 0;
#pragma unroll
    for (int k = 0; k < 7; ++k) {
        int v = (lo + k < NBKT) ? bcnt[lo + k] : 0;
        loc[k] = v;
        sum += v;
    }
    s[t] = sum;
    __syncthreads();
    for (int d = 1; d < 256; d <<= 1) {
        int x = (t >= d) ? s[t - d] : 0;
        __syncthreads();
        s[t] += x;
        __syncthreads();
    }
    int run = s[t] - sum;   // exclusive chunk base
#pragma unroll
    for (int k = 0; k < 7; ++k) {
        if (lo + k < NBKT) {
            bbase[lo + k] = run;
            run += loc[k];
        }
    }
    for (int i = t; i < NBKT; i += 256) bcur[i] = 0;
    if (t == 0) {
        bbase[NBKT] = NEDGES;
        offs[NNODES] = NEDGES;
    }
}

// Phase 2: bin edges into bucket regions as packed (c_local<<17 | r), 23 bits
__global__ __launch_bounds__(256) void k_binA(const int* __restrict__ ei,
                                              const int* __restrict__ bbase, int* __restrict__ bcur,
                                              unsigned int* __restrict__ pairs) {
    int e0 = (blockIdx.x * 256 + threadIdx.x) * 4;
    int4 r4 = *(const int4*)&ei[e0];
    int4 c4 = *(const int4*)&ei[NEDGES + e0];
    int rr[4] = {r4.x, r4.y, r4.z, r4.w};
    int cc[4] = {c4.x, c4.y, c4.z, c4.w};
#pragma unroll
    for (int j = 0; j < 4; ++j) {
        int c = cc[j];
        int b = c >> 6;
        int p = bbase[b] + atomicAdd(&bcur[b], 1);
        pairs[p] = ((unsigned int)(c & 63) << 17) | (unsigned int)rr[j];
    }
}

// Phase 3: per-bucket LDS sort -> coalesced csr_row write; also emits offs + dinv
__global__ __launch_bounds__(256) void k_binB(const unsigned int* __restrict__ pairs,
                                              const int* __restrict__ bbase,
                                              int* __restrict__ csr_row,
                                              int* __restrict__ offs, float* __restrict__ dinv) {
    __shared__ unsigned int ps[BCAP];
    __shared__ int outr[BCAP];
    __shared__ int cl_cnt[64];
    __shared__ int cl_excl[64];
    int bkt = blockIdx.x;
    int tid = threadIdx.x;
    int base = bbase[bkt];
    int count = bbase[bkt + 1] - base;
    if (count > BCAP) count = BCAP;   // statistically unreachable
    if (tid < 64) cl_cnt[tid] = 0;
    __syncthreads();
    for (int t = tid; t < count; t += 256) {
        unsigned int pk = pairs[base + t];
        ps[t] = pk;
        atomicAdd(&cl_cnt[pk >> 17], 1);
    }
    __syncthreads();
    if (tid == 0) {
        int run = 0;
        for (int k = 0; k < 64; ++k) {
            cl_excl[k] = run;
            run += cl_cnt[k];
        }
    }
    __syncthreads();
    if (tid < 64) {
        int node = (bkt << 6) + tid;
        offs[node] = base + cl_excl[tid];
        dinv[node] = 1.0f / sqrtf((float)(cl_cnt[tid] + 1));   // +1 self loop
        cl_cnt[tid] = cl_excl[tid];   // becomes running cursor
    }
    __syncthreads();
    for (int t = tid; t < count; t += 256) {
        unsigned int pk = ps[t];
        int cl = (int)(pk >> 17);
        int pos = atomicAdd(&cl_cnt[cl], 1);
        outr[pos] = (int)(pk & 0x1FFFFu);
    }
    __syncthreads();
    for (int t = tid; t < count; t += 256) csr_row[base + t] = outr[t];
}

// ---------------- layer-0 GEMM: hs = (x @ W0) * dinv[row] ----------------
__global__ __launch_bounds__(256) void k_gemm256(const float* __restrict__ x,
                                                 const float* __restrict__ W,
                                                 const float* __restrict__ dinv,
                                                 float* __restrict__ hs) {
    __shared__ float Xs[32 * 256];   // 32 KB
    __shared__ float Ws[256 * 32];   // 32 KB, [k][col]
    int tid = threadIdx.x;
    int row0 = blockIdx.x * 32;
    const float4* Wv = (const float4*)W;
    const float4* Xv = (const float4*)(x + (size_t)row0 * 256);
    float4* Wsv = (float4*)Ws;
    float4* Xsv = (float4*)Xs;
    for (int i = tid; i < 2048; i += 256) {
        Wsv[i] = Wv[i];
        Xsv[i] = Xv[i];
    }
    __syncthreads();
    int colid = tid & 31;
    int rs = tid >> 5;
    float acc0 = 0.f, acc1 = 0.f, acc2 = 0.f, acc3 = 0.f;
    for (int k = 0; k < 256; k += 4) {
        float4 x0 = *(const float4*)&Xs[(rs) * 256 + k];
        float4 x1 = *(const float4*)&Xs[(rs + 8) * 256 + k];
        float4 x2 = *(const float4*)&Xs[(rs + 16) * 256 + k];
        float4 x3 = *(const float4*)&Xs[(rs + 24) * 256 + k];
        float w0 = Ws[(k + 0) * 32 + colid];
        float w1 = Ws[(k + 1) * 32 + colid];
        float w2 = Ws[(k + 2) * 32 + colid];
        float w3 = Ws[(k + 3) * 32 + colid];
        acc0 += x0.x * w0 + x0.y * w1 + x0.z * w2 + x0.w * w3;
        acc1 += x1.x * w0 + x1.y * w1 + x1.z * w2 + x1.w * w3;
        acc2 += x2.x * w0 + x2.y * w1 + x2.z * w2 + x2.w * w3;
        acc3 += x3.x * w0 + x3.y * w1 + x3.z * w2 + x3.w * w3;
    }
    hs[(size_t)(row0 + rs) * 32 + colid]      = acc0 * dinv[row0 + rs];
    hs[(size_t)(row0 + rs + 8) * 32 + colid]  = acc1 * dinv[row0 + rs + 8];
    hs[(size_t)(row0 + rs + 16) * 32 + colid] = acc2 * dinv[row0 + rs + 16];
    hs[(size_t)(row0 + rs + 24) * 32 + colid] = acc3 * dinv[row0 + rs + 24];
}

// ---------------- 32x32 GEMM: hs = (h @ W) * dinv[row] ----------------
__global__ __launch_bounds__(256) void k_gemm32(const float* __restrict__ h,
                                                const float* __restrict__ W,
                                                const float* __restrict__ dinv,
                                                float* __restrict__ hs) {
    __shared__ float Hs[64 * 32];
    __shared__ float Ws[32 * 32];
    int tid = threadIdx.x;
    int row0 = blockIdx.x * 64;
    const float4* Hv = (const float4*)(h + (size_t)row0 * 32);
    float4* Hsv = (float4*)Hs;
    for (int i = tid; i < 512; i += 256) Hsv[i] = Hv[i];
    for (int i = tid; i < 1024; i += 256) Ws[i] = W[i];
    __syncthreads();
    int colid = tid & 31;
    int rs = tid >> 5;
    for (int j = 0; j < 8; ++j) {
        int rl = rs * 8 + j;
        float acc = 0.f;
#pragma unroll
        for (int k = 0; k < 32; ++k) acc += Hs[rl * 32 + k] * Ws[k * 32 + colid];
        hs[(size_t)(row0 + rl) * 32 + colid] = acc * dinv[row0 + rl];
    }
}

// ---------------- aggregation (32 ch), software-pipelined 8-wide gather ----------------
__global__ __launch_bounds__(256) void k_agg32(const float* __restrict__ hs,
                                               const int* __restrict__ offs,
                                               const int* __restrict__ csr_row,
                                               const float* __restrict__ dinv,
                                               const float* __restrict__ bias,
                                               float* __restrict__ h_out,
                                               float* __restrict__ cs, int col_base) {
    int node = blockIdx.x * 8 + (threadIdx.x >> 5);
    int ch = threadIdx.x & 31;
    int s = offs[node], e = offs[node + 1];
    int cnt = e - s;
    float a0 = hs[(size_t)node * 32 + ch];   // self-loop (pre-scaled)
    float a1 = 0.f, a2 = 0.f, a3 = 0.f;
    int nfull = cnt >> 3;
    if (nfull > 0) {
        int idx[8];
#pragma unroll
        for (int j = 0; j < 8; ++j) idx[j] = csr_row[s + j];
        int p = s + 8;
        for (int b = 1; b < nfull; ++b, p += 8) {
            int nxt[8];
#pragma unroll
            for (int j = 0; j < 8; ++j) nxt[j] = csr_row[p + j];
            float v0 = hs[(size_t)idx[0] * 32 + ch];
            float v1 = hs[(size_t)idx[1] * 32 + ch];
            float v2 = hs[(size_t)idx[2] * 32 + ch];
            float v3 = hs[(size_t)idx[3] * 32 + ch];
            float v4 = hs[(size_t)idx[4] * 32 + ch];
            float v5 = hs[(size_t)idx[5] * 32 + ch];
            float v6 = hs[(size_t)idx[6] * 32 + ch];
            float v7 = hs[(size_t)idx[7] * 32 + ch];
            a0 += v0 + v4;
            a1 += v1 + v5;
            a2 += v2 + v6;
            a3 += v3 + v7;
#pragma unroll
            for (int j = 0; j < 8; ++j) idx[j] = nxt[j];
        }
        {
            float v0 = hs[(size_t)idx[0] * 32 + ch];
            float v1 = hs[(size_t)idx[1] * 32 + ch];
            float v2 = hs[(size_t)idx[2] * 32 + ch];
            float v3 = hs[(size_t)idx[3] * 32 + ch];
            float v4 = hs[(size_t)idx[4] * 32 + ch];
            float v5 = hs[(size_t)idx[5] * 32 + ch];
            float v6 = hs[(size_t)idx[6] * 32 + ch];
            float v7 = hs[(size_t)idx[7] * 32 + ch];
            a0 += v0 + v4;
            a1 += v1 + v5;
            a2 += v2 + v6;
            a3 += v3 + v7;
        }
    }
    for (int t = s + (nfull << 3); t < e; ++t) a0 += hs[(size_t)csr_row[t] * 32 + ch];
    float acc = (a0 + a1) + (a2 + a3);
    float v = tanhf(dinv[node] * acc + bias[ch]);
    h_out[(size_t)node * 32 + ch] = v;
    cs[(size_t)node * DTOTC + col_base + ch] = v;
}

// ---------------- layer-3 (32 -> 1) ----------------
__global__ void k_gemv1(const float* __restrict__ h, const float* __restrict__ W3,
                        const float* __restrict__ dinv, float* __restrict__ hs4) {
    int i = blockIdx.x * 256 + threadIdx.x;
    if (i >= NNODES) return;
    float acc = 0.f;
#pragma unroll
    for (int k = 0; k < 32; ++k) acc += h[(size_t)i * 32 + k] * W3[k];
    hs4[i] = acc * dinv[i];
}

__global__ void k_agg1(const float* __restrict__ hs4, const int* __restrict__ offs,
                       const int* __restrict__ csr_row, const float* __restrict__ dinv,
                       const float* __restrict__ b3, float* __restrict__ cs) {
    int node = blockIdx.x * 256 + threadIdx.x;
    if (node >= NNODES) return;
    int s = offs[node], e = offs[node + 1];
    float a0 = hs4[node], a1 = 0.f, a2 = 0.f, a3 = 0.f;
    int i = s;
    for (; i + 8 <= e; i += 8) {
        int idx[8];
#pragma unroll
        for (int j = 0; j < 8; ++j) idx[j] = csr_row[i + j];
        a0 += hs4[idx[0]] + hs4[idx[4]];
        a1 += hs4[idx[1]] + hs4[idx[5]];
        a2 += hs4[idx[2]] + hs4[idx[6]];
        a3 += hs4[idx[3]] + hs4[idx[7]];
    }
    for (; i < e; ++i) a0 += hs4[csr_row[i]];
    float acc = (a0 + a1) + (a2 + a3);
    cs[(size_t)node * DTOTC + 96] = tanhf(dinv[node] * acc + b3[0]);
}

// ---------------- fused sortpool -> conv1 -> maxpool -> conv2 -> lin1 -> graph sum ----------------
__global__ __launch_bounds__(128) void k_sub(const float* __restrict__ cs,
                                             const float* __restrict__ c1w, const float* __restrict__ c1b,
                                             const float* __restrict__ c2w, const float* __restrict__ c2b,
                                             const float* __restrict__ l1w, const float* __restrict__ l1b,
                                             float* __restrict__ gsum) {
    __shared__ float csb[MSZ * DTOTC];
    __shared__ float c1ws[16 * DTOTC];
    __shared__ float c2ws[32 * 16 * 5];
    __shared__ float h1s[16 * 30];
    __shared__ float m1s[16 * 15];
    __shared__ float h2s[352];
    __shared__ int ord[KTOP];
    int tid = threadIdx.x;
    int sub = blockIdx.x;
    const float* src = cs + (size_t)sub * (MSZ * DTOTC);
    for (int i = tid; i < MSZ * DTOTC; i += 128) csb[i] = src[i];
    for (int i = tid; i < 16 * DTOTC; i += 128) c1ws[i] = c1w[i];
    for (int i = tid; i < 32 * 16 * 5; i += 128) c2ws[i] = c2w[i];
    __syncthreads();
    if (tid < MSZ) {
        float v = csb[tid * DTOTC + 96];
        int rank = 0;
        for (int j = 0; j < MSZ; ++j) {
            float vj = csb[j * DTOTC + 96];
            rank += (vj > v) || (vj == v && j < tid);
        }
        if (rank < KTOP) ord[rank] = tid;
    }
    __syncthreads();
    for (int p = tid; p < 16 * 30; p += 128) {
        int o = p / 30, k = p % 30;
        const float* xr = &csb[ord[k] * DTOTC];
        const float* wr = &c1ws[o * DTOTC];
        float acc = c1b[o];
        for (int d = 0; d < DTOTC; ++d) acc += xr[d] * wr[d];
        h1s[o * 30 + k] = fmaxf(acc, 0.f);
    }
    __syncthreads();
    for (int p = tid; p < 16 * 15; p += 128) {
        int o = p / 15, j = p % 15;
        m1s[p] = fmaxf(h1s[o * 30 + 2 * j], h1s[o * 30 + 2 * j + 1]);
    }
    __syncthreads();
    for (int p = tid; p < 352; p += 128) {
        int o = p / 11, t = p % 11;
        float acc = c2b[o];
        for (int ic = 0; ic < 16; ++ic) {
#pragma unroll
            for (int j = 0; j < 5; ++j)
                acc += m1s[ic * 15 + t + j] * c2ws[(o * 16 + ic) * 5 + j];
        }
        h2s[p] = fmaxf(acc, 0.f);
    }
    __syncthreads();
    {
        int c = tid;
        float acc = l1b[c];
        for (int i = 0; i < 352; ++i) acc += h2s[i] * l1w[i * 128 + c];
        atomicAdd(&gsum[(sub >> 5) * 128 + c], acc);
    }
}

// ---------------- head: mean -> relu -> lin2 -> log_softmax ----------------
__global__ __launch_bounds__(128) void k_head(const float* __restrict__ gsum,
                                              const float* __restrict__ l2w,
                                              const float* __restrict__ l2b,
                                              float* __restrict__ out) {
    __shared__ float g[128];
    __shared__ float os[10];
    int b = blockIdx.x, tid = threadIdx.x;
    g[tid] = fmaxf(gsum[b * 128 + tid] * (1.0f / 32.0f), 0.f);
    __syncthreads();
    if (tid < 10) {
        float acc = l2b[tid];
        for (int k = 0; k < 128; ++k) acc += g[k] * l2w[k * 10 + tid];
        os[tid] = acc;
    }
    __syncthreads();
    if (tid == 0) {
        float m = os[0];
        for (int c = 1; c < 10; ++c) m = fmaxf(m, os[c]);
        float sum = 0.f;
        for (int c = 0; c < 10; ++c) sum += expf(os[c] - m);
        float l = m + logf(sum);
        for (int c = 0; c < 10; ++c) out[b * 10 + c] = os[c] - l;
    }
}

extern "C" void kernel_launch(void* const* d_in, const int* in_sizes, int n_in,
                              void* d_out, int out_size, void* d_ws, size_t ws_size,
                              hipStream_t stream) {
    const float* x   = (const float*)d_in[0];
    const int*   ei  = (const int*)d_in[1];
    const float* W0  = (const float*)d_in[2];
    const float* b0  = (const float*)d_in[3];
    const float* W1  = (const float*)d_in[4];
    const float* b1  = (const float*)d_in[5];
    const float* W2  = (const float*)d_in[6];
    const float* b2  = (const float*)d_in[7];
    const float* W3  = (const float*)d_in[8];
    const float* b3  = (const float*)d_in[9];
    const float* c1w = (const float*)d_in[10];
    const float* c1b = (const float*)d_in[11];
    const float* c2w = (const float*)d_in[12];
    const float* c2b = (const float*)d_in[13];
    const float* l1w = (const float*)d_in[14];
    const float* l1b = (const float*)d_in[15];
    const float* l2w = (const float*)d_in[16];
    const float* l2b = (const float*)d_in[17];
    float* out = (float*)d_out;

    char* ws = (char*)d_ws;
    size_t off = 0;
    auto alloc = [&](size_t bytes) {
        void* p = ws + off;
        off += (bytes + 255) & ~(size_t)255;
        return p;
    };
    int*   bcnt    = (int*)alloc(NBKT * sizeof(int));
    int*   bbase   = (int*)alloc((NBKT + 1) * sizeof(int));
    int*   bcur    = (int*)alloc(NBKT * sizeof(int));
    int*   offs    = (int*)alloc((NNODES + 1) * sizeof(int));
    float* dinv    = (float*)alloc((size_t)NNODES * sizeof(float));
    int*   csr_row = (int*)alloc((size_t)NEDGES * sizeof(int));
    float* bufA    = (float*)alloc((size_t)NNODES * 32 * sizeof(float));
    float* bufB    = (float*)alloc((size_t)NNODES * 32 * sizeof(float));
    float* cs      = (float*)alloc((size_t)NNODES * DTOTC * sizeof(float));
    float* hs4     = (float*)alloc((size_t)NNODES * sizeof(float));
    float* gsum    = (float*)alloc(64 * 128 * sizeof(float));
    // pairs buffer aliases cs: consumed by k_binB before cs is first written (k_agg32)
    unsigned int* pairs = (unsigned int*)cs;

    hipMemsetAsync(bcnt, 0, NBKT * sizeof(int), stream);
    hipMemsetAsync(gsum, 0, 64 * 128 * sizeof(float), stream);

    const int* col = ei + NEDGES;

    // CSR build (two-level counting sort; also emits offs + dinv)
    k_histB<<<NEDGES / 2048, 256, 0, stream>>>(col, bcnt);
    k_scanB<<<1, 256, 0, stream>>>(bcnt, bbase, bcur, offs);
    k_binA<<<NEDGES / 1024, 256, 0, stream>>>(ei, bbase, bcur, pairs);
    k_binB<<<NBKT, 256, 0, stream>>>(pairs, bbase, csr_row, offs, dinv);

    // layer 0: 256 -> 32
    k_gemm256<<<NNODES / 32, 256, 0, stream>>>(x, W0, dinv, bufA);
    k_agg32<<<NNODES / 8, 256, 0, stream>>>(bufA, offs, csr_row, dinv, b0, bufB, cs, 0);
    // layer 1: 32 -> 32
    k_gemm32<<<NNODES / 64, 256, 0, stream>>>(bufB, W1, dinv, bufA);
    k_agg32<<<NNODES / 8, 256, 0, stream>>>(bufA, offs, csr_row, dinv, b1, bufB, cs, 32);
    // layer 2: 32 -> 32
    k_gemm32<<<NNODES / 64, 256, 0, stream>>>(bufB, W2, dinv, bufA);
    k_agg32<<<NNODES / 8, 256, 0, stream>>>(bufA, offs, csr_row, dinv, b2, bufB, cs, 64);
    // layer 3: 32 -> 1
    k_gemv1<<<NNODES / 256, 256, 0, stream>>>(bufB, W3, dinv, hs4);
    k_agg1<<<NNODES / 256, 256, 0, stream>>>(hs4, offs, csr_row, dinv, b3, cs);

    // sortpool + conv stack + lin1 + per-graph sum
    k_sub<<<NSUB, 128, 0, stream>>>(cs, c1w, c1b, c2w, c2b, l1w, l1b, gsum);
    // mean -> relu -> lin2 -> log_softmax
    k_head<<<64, 128, 0, stream>>>(gsum, l2w, l2b, out);
}

// Round 6
// 930.472 us; speedup vs baseline: 1.2346x; 1.1729x over previous
//
#include <hip/hip_runtime.h>
#include <math.h>

// Problem constants (fixed by reference setup_inputs)
#define NNODES 102400      // B*S*M = 64*32*50
#define NEDGES 3276800
#define FIN 256
#define DTOTC 97
#define KTOP 30
#define NSUB 2048          // B*S
#define MSZ 50
#define NBKT 1600          // dst-range buckets of 64 nodes each
#define BCAP 3584          // bucket staging cap (mean 2048, sigma ~45 -> 34 sigma)
#define EPB 16384          // edges per binning block

// ---------------- CSR build: two-level counting sort ----------------
// Phase 0: bucket histogram (LDS-local then flush)
__global__ __launch_bounds__(256) void k_histB(const int* __restrict__ col, int* __restrict__ bcnt) {
    __shared__ int h[NBKT];
    int tid = threadIdx.x;
    for (int i = tid; i < NBKT; i += 256) h[i] = 0;
    __syncthreads();
    int e0 = blockIdx.x * 2048 + tid * 8;
    int4 c0 = *(const int4*)&col[e0];
    int4 c1 = *(const int4*)&col[e0 + 4];
    atomicAdd(&h[c0.x >> 6], 1);
    atomicAdd(&h[c0.y >> 6], 1);
    atomicAdd(&h[c0.z >> 6], 1);
    atomicAdd(&h[c0.w >> 6], 1);
    atomicAdd(&h[c1.x >> 6], 1);
    atomicAdd(&h[c1.y >> 6], 1);
    atomicAdd(&h[c1.z >> 6], 1);
    atomicAdd(&h[c1.w >> 6], 1);
    __syncthreads();
    for (int i = tid; i < NBKT; i += 256) {
        int v = h[i];
        if (v) atomicAdd(&bcnt[i], v);
    }
}

// Phase 1: exclusive scan of 1600 bucket counts (single block), init cursors + sentinels
__global__ __launch_bounds__(256) void k_scanB(const int* __restrict__ bcnt,
                                               int* __restrict__ bbase, int* __restrict__ bcur,
                                               int* __restrict__ offs) {
    __shared__ int s[256];
    int t = threadIdx.x;
    int lo = t * 7;
    int loc[7];
    int sum = 0;
#pragma unroll
    for (int k = 0; k < 7; ++k) {
        int v = (lo + k < NBKT) ? bcnt[lo + k] : 0;
        loc[k] = v;
        sum += v;
    }
    s[t] = sum;
    __syncthreads();
    for (int d = 1; d < 256; d <<= 1) {
        int x = (t >= d) ? s[t - d] : 0;
        __syncthreads();
        s[t] += x;
        __syncthreads();
    }
    int run = s[t] - sum;   // exclusive chunk base
#pragma unroll
    for (int k = 0; k < 7; ++k) {
        if (lo + k < NBKT) {
            bbase[lo + k] = run;
            run += loc[k];
        }
    }
    for (int i = t; i < NBKT; i += 256) bcur[i] = 0;
    if (t == 0) {
        bbase[NBKT] = NEDGES;
        offs[NNODES] = NEDGES;
    }
}

// Phase 2: block-aggregated binning. Each block stages EPB edges bucket-sorted in
// LDS, reserves per-bucket runs with ONE global atomic each, writes runs out.
__global__ __launch_bounds__(512) void k_binA(const int* __restrict__ ei,
                                              const int* __restrict__ bbase, int* __restrict__ bcur,
                                              unsigned int* __restrict__ pairs) {
    __shared__ int hist[NBKT];          // histogram, then reused as running cursor / run-end
    __shared__ int lbase[NBKT];         // block-local exclusive scan (run start)
    __shared__ int s[512];
    __shared__ unsigned int stage[EPB]; // 64 KB bucket-sorted staging
    int tid = threadIdx.x;
    int e0 = blockIdx.x * EPB;
    const int* rowp = ei + e0;
    const int* colp = ei + NEDGES + e0;
    for (int i = tid; i < NBKT; i += 512) hist[i] = 0;
    __syncthreads();
    // pass 1: histogram of dst-buckets
#pragma unroll
    for (int it = 0; it < EPB / 2048; ++it) {    // 8 iters, 2048 edges each
        int4 c = *(const int4*)&colp[it * 2048 + tid * 4];
        atomicAdd(&hist[c.x >> 6], 1);
        atomicAdd(&hist[c.y >> 6], 1);
        atomicAdd(&hist[c.z >> 6], 1);
        atomicAdd(&hist[c.w >> 6], 1);
    }
    __syncthreads();
    // block-wide exclusive scan of hist -> lbase
    {
        int base4 = tid * 4;
        int l0 = 0, l1 = 0, l2 = 0, l3 = 0, sum = 0;
        if (base4 < NBKT) {
            l0 = hist[base4 + 0];
            l1 = hist[base4 + 1];
            l2 = hist[base4 + 2];
            l3 = hist[base4 + 3];
            sum = l0 + l1 + l2 + l3;
        }
        s[tid] = sum;
        __syncthreads();
        for (int d = 1; d < 512; d <<= 1) {
            int x = (tid >= d) ? s[tid - d] : 0;
            __syncthreads();
            s[tid] += x;
            __syncthreads();
        }
        int run = s[tid] - sum;
        if (base4 < NBKT) {
            lbase[base4 + 0] = run;
            lbase[base4 + 1] = run + l0;
            lbase[base4 + 2] = run + l0 + l1;
            lbase[base4 + 3] = run + l0 + l1 + l2;
        }
        __syncthreads();
        // hist becomes running cursor
        if (base4 < NBKT) {
            hist[base4 + 0] = lbase[base4 + 0];
            hist[base4 + 1] = lbase[base4 + 1];
            hist[base4 + 2] = lbase[base4 + 2];
            hist[base4 + 3] = lbase[base4 + 3];
        }
    }
    __syncthreads();
    // pass 2: place packed records bucket-sorted into stage
#pragma unroll
    for (int it = 0; it < EPB / 2048; ++it) {
        int4 r = *(const int4*)&rowp[it * 2048 + tid * 4];
        int4 c = *(const int4*)&colp[it * 2048 + tid * 4];
        int p;
        p = atomicAdd(&hist[c.x >> 6], 1);
        stage[p] = ((unsigned int)(c.x & 63) << 17) | (unsigned int)r.x;
        p = atomicAdd(&hist[c.y >> 6], 1);
        stage[p] = ((unsigned int)(c.y & 63) << 17) | (unsigned int)r.y;
        p = atomicAdd(&hist[c.z >> 6], 1);
        stage[p] = ((unsigned int)(c.z & 63) << 17) | (unsigned int)r.z;
        p = atomicAdd(&hist[c.w >> 6], 1);
        stage[p] = ((unsigned int)(c.w & 63) << 17) | (unsigned int)r.w;
    }
    __syncthreads();
    // pass 3: warp-per-bucket reservation + run writeout
    int lane = tid & 63, wid = tid >> 6;      // 8 warps
    for (int b = wid; b < NBKT; b += 8) {
        int lo = lbase[b];
        int hi = hist[b];                      // run end after pass 2
        int cnt = hi - lo;
        int g = 0;
        if (lane == 0 && cnt > 0) g = bbase[b] + atomicAdd(&bcur[b], cnt);
        g = __shfl(g, 0);
        for (int j = lane; j < cnt; j += 64) pairs[g + j] = stage[lo + j];
    }
}

// Phase 3: per-bucket LDS sort -> coalesced csr_row write; also emits offs + dinv
__global__ __launch_bounds__(256) void k_binB(const unsigned int* __restrict__ pairs,
                                              const int* __restrict__ bbase,
                                              int* __restrict__ csr_row,
                                              int* __restrict__ offs, float* __restrict__ dinv) {
    __shared__ unsigned int ps[BCAP];
    __shared__ int outr[BCAP];
    __shared__ int cl_cnt[64];
    __shared__ int cl_excl[64];
    int bkt = blockIdx.x;
    int tid = threadIdx.x;
    int base = bbase[bkt];
    int count = bbase[bkt + 1] - base;
    if (count > BCAP) count = BCAP;   // statistically unreachable
    if (tid < 64) cl_cnt[tid] = 0;
    __syncthreads();
    for (int t = tid; t < count; t += 256) {
        unsigned int pk = pairs[base + t];
        ps[t] = pk;
        atomicAdd(&cl_cnt[pk >> 17], 1);
    }
    __syncthreads();
    if (tid == 0) {
        int run = 0;
        for (int k = 0; k < 64; ++k) {
            cl_excl[k] = run;
            run += cl_cnt[k];
        }
    }
    __syncthreads();
    if (tid < 64) {
        int node = (bkt << 6) + tid;
        offs[node] = base + cl_excl[tid];
        dinv[node] = 1.0f / sqrtf((float)(cl_cnt[tid] + 1));   // +1 self loop
        cl_cnt[tid] = cl_excl[tid];   // becomes running cursor
    }
    __syncthreads();
    for (int t = tid; t < count; t += 256) {
        unsigned int pk = ps[t];
        int cl = (int)(pk >> 17);
        int pos = atomicAdd(&cl_cnt[cl], 1);
        outr[pos] = (int)(pk & 0x1FFFFu);
    }
    __syncthreads();
    for (int t = tid; t < count; t += 256) csr_row[base + t] = outr[t];
}

// ---------------- layer-0 GEMM: hs = (x @ W0) * dinv[row] ----------------
__global__ __launch_bounds__(256) void k_gemm256(const float* __restrict__ x,
                                                 const float* __restrict__ W,
                                                 const float* __restrict__ dinv,
                                                 float* __restrict__ hs) {
    __shared__ float Xs[32 * 256];   // 32 KB
    __shared__ float Ws[256 * 32];   // 32 KB, [k][col]
    int tid = threadIdx.x;
    int row0 = blockIdx.x * 32;
    const float4* Wv = (const float4*)W;
    const float4* Xv = (const float4*)(x + (size_t)row0 * 256);
    float4* Wsv = (float4*)Ws;
    float4* Xsv = (float4*)Xs;
    for (int i = tid; i < 2048; i += 256) {
        Wsv[i] = Wv[i];
        Xsv[i] = Xv[i];
    }
    __syncthreads();
    int colid = tid & 31;
    int rs = tid >> 5;
    float acc0 = 0.f, acc1 = 0.f, acc2 = 0.f, acc3 = 0.f;
    for (int k = 0; k < 256; k += 4) {
        float4 x0 = *(const float4*)&Xs[(rs) * 256 + k];
        float4 x1 = *(const float4*)&Xs[(rs + 8) * 256 + k];
        float4 x2 = *(const float4*)&Xs[(rs + 16) * 256 + k];
        float4 x3 = *(const float4*)&Xs[(rs + 24) * 256 + k];
        float w0 = Ws[(k + 0) * 32 + colid];
        float w1 = Ws[(k + 1) * 32 + colid];
        float w2 = Ws[(k + 2) * 32 + colid];
        float w3 = Ws[(k + 3) * 32 + colid];
        acc0 += x0.x * w0 + x0.y * w1 + x0.z * w2 + x0.w * w3;
        acc1 += x1.x * w0 + x1.y * w1 + x1.z * w2 + x1.w * w3;
        acc2 += x2.x * w0 + x2.y * w1 + x2.z * w2 + x2.w * w3;
        acc3 += x3.x * w0 + x3.y * w1 + x3.z * w2 + x3.w * w3;
    }
    hs[(size_t)(row0 + rs) * 32 + colid]      = acc0 * dinv[row0 + rs];
    hs[(size_t)(row0 + rs + 8) * 32 + colid]  = acc1 * dinv[row0 + rs + 8];
    hs[(size_t)(row0 + rs + 16) * 32 + colid] = acc2 * dinv[row0 + rs + 16];
    hs[(size_t)(row0 + rs + 24) * 32 + colid] = acc3 * dinv[row0 + rs + 24];
}

// ---------------- 32x32 GEMM: hs = (h @ W) * dinv[row] ----------------
__global__ __launch_bounds__(256) void k_gemm32(const float* __restrict__ h,
                                                const float* __restrict__ W,
                                                const float* __restrict__ dinv,
                                                float* __restrict__ hs) {
    __shared__ float Hs[64 * 32];
    __shared__ float Ws[32 * 32];
    int tid = threadIdx.x;
    int row0 = blockIdx.x * 64;
    const float4* Hv = (const float4*)(h + (size_t)row0 * 32);
    float4* Hsv = (float4*)Hs;
    for (int i = tid; i < 512; i += 256) Hsv[i] = Hv[i];
    for (int i = tid; i < 1024; i += 256) Ws[i] = W[i];
    __syncthreads();
    int colid = tid & 31;
    int rs = tid >> 5;
    for (int j = 0; j < 8; ++j) {
        int rl = rs * 8 + j;
        float acc = 0.f;
#pragma unroll
        for (int k = 0; k < 32; ++k) acc += Hs[rl * 32 + k] * Ws[k * 32 + colid];
        hs[(size_t)(row0 + rl) * 32 + colid] = acc * dinv[row0 + rl];
    }
}

// ---------------- aggregation (32 ch), software-pipelined 8-wide gather ----------------
__global__ __launch_bounds__(256) void k_agg32(const float* __restrict__ hs,
                                               const int* __restrict__ offs,
                                               const int* __restrict__ csr_row,
                                               const float* __restrict__ dinv,
                                               const float* __restrict__ bias,
                                               float* __restrict__ h_out,
                                               float* __restrict__ cs, int col_base) {
    int node = blockIdx.x * 8 + (threadIdx.x >> 5);
    int ch = threadIdx.x & 31;
    int s = offs[node], e = offs[node + 1];
    int cnt = e - s;
    float a0 = hs[(size_t)node * 32 + ch];   // self-loop (pre-scaled)
    float a1 = 0.f, a2 = 0.f, a3 = 0.f;
    int nfull = cnt >> 3;
    if (nfull > 0) {
        int idx[8];
#pragma unroll
        for (int j = 0; j < 8; ++j) idx[j] = csr_row[s + j];
        int p = s + 8;
        for (int b = 1; b < nfull; ++b, p += 8) {
            int nxt[8];
#pragma unroll
            for (int j = 0; j < 8; ++j) nxt[j] = csr_row[p + j];
            float v0 = hs[(size_t)idx[0] * 32 + ch];
            float v1 = hs[(size_t)idx[1] * 32 + ch];
            float v2 = hs[(size_t)idx[2] * 32 + ch];
            float v3 = hs[(size_t)idx[3] * 32 + ch];
            float v4 = hs[(size_t)idx[4] * 32 + ch];
            float v5 = hs[(size_t)idx[5] * 32 + ch];
            float v6 = hs[(size_t)idx[6] * 32 + ch];
            float v7 = hs[(size_t)idx[7] * 32 + ch];
            a0 += v0 + v4;
            a1 += v1 + v5;
            a2 += v2 + v6;
            a3 += v3 + v7;
#pragma unroll
            for (int j = 0; j < 8; ++j) idx[j] = nxt[j];
        }
        {
            float v0 = hs[(size_t)idx[0] * 32 + ch];
            float v1 = hs[(size_t)idx[1] * 32 + ch];
            float v2 = hs[(size_t)idx[2] * 32 + ch];
            float v3 = hs[(size_t)idx[3] * 32 + ch];
            float v4 = hs[(size_t)idx[4] * 32 + ch];
            float v5 = hs[(size_t)idx[5] * 32 + ch];
            float v6 = hs[(size_t)idx[6] * 32 + ch];
            float v7 = hs[(size_t)idx[7] * 32 + ch];
            a0 += v0 + v4;
            a1 += v1 + v5;
            a2 += v2 + v6;
            a3 += v3 + v7;
        }
    }
    for (int t = s + (nfull << 3); t < e; ++t) a0 += hs[(size_t)csr_row[t] * 32 + ch];
    float acc = (a0 + a1) + (a2 + a3);
    float v = tanhf(dinv[node] * acc + bias[ch]);
    h_out[(size_t)node * 32 + ch] = v;
    cs[(size_t)node * DTOTC + col_base + ch] = v;
}

// ---------------- layer-3 (32 -> 1) ----------------
__global__ void k_gemv1(const float* __restrict__ h, const float* __restrict__ W3,
                        const float* __restrict__ dinv, float* __restrict__ hs4) {
    int i = blockIdx.x * 256 + threadIdx.x;
    if (i >= NNODES) return;
    float acc = 0.f;
#pragma unroll
    for (int k = 0; k < 32; ++k) acc += h[(size_t)i * 32 + k] * W3[k];
    hs4[i] = acc * dinv[i];
}

__global__ void k_agg1(const float* __restrict__ hs4, const int* __restrict__ offs,
                       const int* __restrict__ csr_row, const float* __restrict__ dinv,
                       const float* __restrict__ b3, float* __restrict__ cs) {
    int node = blockIdx.x * 256 + threadIdx.x;
    if (node >= NNODES) return;
    int s = offs[node], e = offs[node + 1];
    float a0 = hs4[node], a1 = 0.f, a2 = 0.f, a3 = 0.f;
    int i = s;
    for (; i + 8 <= e; i += 8) {
        int idx[8];
#pragma unroll
        for (int j = 0; j < 8; ++j) idx[j] = csr_row[i + j];
        a0 += hs4[idx[0]] + hs4[idx[4]];
        a1 += hs4[idx[1]] + hs4[idx[5]];
        a2 += hs4[idx[2]] + hs4[idx[6]];
        a3 += hs4[idx[3]] + hs4[idx[7]];
    }
    for (; i < e; ++i) a0 += hs4[csr_row[i]];
    float acc = (a0 + a1) + (a2 + a3);
    cs[(size_t)node * DTOTC + 96] = tanhf(dinv[node] * acc + b3[0]);
}

// ---------------- fused sortpool -> conv1 -> maxpool -> conv2 -> lin1 -> graph sum ----------------
__global__ __launch_bounds__(128) void k_sub(const float* __restrict__ cs,
                                             const float* __restrict__ c1w, const float* __restrict__ c1b,
                                             const float* __restrict__ c2w, const float* __restrict__ c2b,
                                             const float* __restrict__ l1w, const float* __restrict__ l1b,
                                             float* __restrict__ gsum) {
    __shared__ float csb[MSZ * DTOTC];
    __shared__ float c1ws[16 * DTOTC];
    __shared__ float c2ws[32 * 16 * 5];
    __shared__ float h1s[16 * 30];
    __shared__ float m1s[16 * 15];
    __shared__ float h2s[352];
    __shared__ int ord[KTOP];
    int tid = threadIdx.x;
    int sub = blockIdx.x;
    const float* src = cs + (size_t)sub * (MSZ * DTOTC);
    for (int i = tid; i < MSZ * DTOTC; i += 128) csb[i] = src[i];
    for (int i = tid; i < 16 * DTOTC; i += 128) c1ws[i] = c1w[i];
    for (int i = tid; i < 32 * 16 * 5; i += 128) c2ws[i] = c2w[i];
    __syncthreads();
    if (tid < MSZ) {
        float v = csb[tid * DTOTC + 96];
        int rank = 0;
        for (int j = 0; j < MSZ; ++j) {
            float vj = csb[j * DTOTC + 96];
            rank += (vj > v) || (vj == v && j < tid);
        }
        if (rank < KTOP) ord[rank] = tid;
    }
    __syncthreads();
    for (int p = tid; p < 16 * 30; p += 128) {
        int o = p / 30, k = p % 30;
        const float* xr = &csb[ord[k] * DTOTC];
        const float* wr = &c1ws[o * DTOTC];
        float acc = c1b[o];
        for (int d = 0; d < DTOTC; ++d) acc += xr[d] * wr[d];
        h1s[o * 30 + k] = fmaxf(acc, 0.f);
    }
    __syncthreads();
    for (int p = tid; p < 16 * 15; p += 128) {
        int o = p / 15, j = p % 15;
        m1s[p] = fmaxf(h1s[o * 30 + 2 * j], h1s[o * 30 + 2 * j + 1]);
    }
    __syncthreads();
    for (int p = tid; p < 352; p += 128) {
        int o = p / 11, t = p % 11;
        float acc = c2b[o];
        for (int ic = 0; ic < 16; ++ic) {
#pragma unroll
            for (int j = 0; j < 5; ++j)
                acc += m1s[ic * 15 + t + j] * c2ws[(o * 16 + ic) * 5 + j];
        }
        h2s[p] = fmaxf(acc, 0.f);
    }
    __syncthreads();
    {
        int c = tid;
        float acc = l1b[c];
        for (int i = 0; i < 352; ++i) acc += h2s[i] * l1w[i * 128 + c];
        atomicAdd(&gsum[(sub >> 5) * 128 + c], acc);
    }
}

// ---------------- head: mean -> relu -> lin2 -> log_softmax ----------------
__global__ __launch_bounds__(128) void k_head(const float* __restrict__ gsum,
                                              const float* __restrict__ l2w,
                                              const float* __restrict__ l2b,
                                              float* __restrict__ out) {
    __shared__ float g[128];
    __shared__ float os[10];
    int b = blockIdx.x, tid = threadIdx.x;
    g[tid] = fmaxf(gsum[b * 128 + tid] * (1.0f / 32.0f), 0.f);
    __syncthreads();
    if (tid < 10) {
        float acc = l2b[tid];
        for (int k = 0; k < 128; ++k) acc += g[k] * l2w[k * 10 + tid];
        os[tid] = acc;
    }
    __syncthreads();
    if (tid == 0) {
        float m = os[0];
        for (int c = 1; c < 10; ++c) m = fmaxf(m, os[c]);
        float sum = 0.f;
        for (int c = 0; c < 10; ++c) sum += expf(os[c] - m);
        float l = m + logf(sum);
        for (int c = 0; c < 10; ++c) out[b * 10 + c] = os[c] - l;
    }
}

extern "C" void kernel_launch(void* const* d_in, const int* in_sizes, int n_in,
                              void* d_out, int out_size, void* d_ws, size_t ws_size,
                              hipStream_t stream) {
    const float* x   = (const float*)d_in[0];
    const int*   ei  = (const int*)d_in[1];
    const float* W0  = (const float*)d_in[2];
    const float* b0  = (const float*)d_in[3];
    const float* W1  = (const float*)d_in[4];
    const float* b1  = (const float*)d_in[5];
    const float* W2  = (const float*)d_in[6];
    const float* b2  = (const float*)d_in[7];
    const float* W3  = (const float*)d_in[8];
    const float* b3  = (const float*)d_in[9];
    const float* c1w = (const float*)d_in[10];
    const float* c1b = (const float*)d_in[11];
    const float* c2w = (const float*)d_in[12];
    const float* c2b = (const float*)d_in[13];
    const float* l1w = (const float*)d_in[14];
    const float* l1b = (const float*)d_in[15];
    const float* l2w = (const float*)d_in[16];
    const float* l2b = (const float*)d_in[17];
    float* out = (float*)d_out;

    char* ws = (char*)d_ws;
    size_t off = 0;
    auto alloc = [&](size_t bytes) {
        void* p = ws + off;
        off += (bytes + 255) & ~(size_t)255;
        return p;
    };
    int*   bcnt    = (int*)alloc(NBKT * sizeof(int));
    int*   bbase   = (int*)alloc((NBKT + 1) * sizeof(int));
    int*   bcur    = (int*)alloc(NBKT * sizeof(int));
    int*   offs    = (int*)alloc((NNODES + 1) * sizeof(int));
    float* dinv    = (float*)alloc((size_t)NNODES * sizeof(float));
    int*   csr_row = (int*)alloc((size_t)NEDGES * sizeof(int));
    float* bufA    = (float*)alloc((size_t)NNODES * 32 * sizeof(float));
    float* bufB    = (float*)alloc((size_t)NNODES * 32 * sizeof(float));
    float* cs      = (float*)alloc((size_t)NNODES * DTOTC * sizeof(float));
    float* hs4     = (float*)alloc((size_t)NNODES * sizeof(float));
    float* gsum    = (float*)alloc(64 * 128 * sizeof(float));
    // pairs buffer aliases cs: consumed by k_binB before cs is first written (k_agg32)
    unsigned int* pairs = (unsigned int*)cs;

    hipMemsetAsync(bcnt, 0, NBKT * sizeof(int), stream);
    hipMemsetAsync(gsum, 0, 64 * 128 * sizeof(float), stream);

    const int* col = ei + NEDGES;

    // CSR build (two-level counting sort; also emits offs + dinv)
    k_histB<<<NEDGES / 2048, 256, 0, stream>>>(col, bcnt);
    k_scanB<<<1, 256, 0, stream>>>(bcnt, bbase, bcur, offs);
    k_binA<<<NEDGES / EPB, 512, 0, stream>>>(ei, bbase, bcur, pairs);
    k_binB<<<NBKT, 256, 0, stream>>>(pairs, bbase, csr_row, offs, dinv);

    // layer 0: 256 -> 32
    k_gemm256<<<NNODES / 32, 256, 0, stream>>>(x, W0, dinv, bufA);
    k_agg32<<<NNODES / 8, 256, 0, stream>>>(bufA, offs, csr_row, dinv, b0, bufB, cs, 0);
    // layer 1: 32 -> 32
    k_gemm32<<<NNODES / 64, 256, 0, stream>>>(bufB, W1, dinv, bufA);
    k_agg32<<<NNODES / 8, 256, 0, stream>>>(bufA, offs, csr_row, dinv, b1, bufB, cs, 32);
    // layer 2: 32 -> 32
    k_gemm32<<<NNODES / 64, 256, 0, stream>>>(bufB, W2, dinv, bufA);
    k_agg32<<<NNODES / 8, 256, 0, stream>>>(bufA, offs, csr_row, dinv, b2, bufB, cs, 64);
    // layer 3: 32 -> 1
    k_gemv1<<<NNODES / 256, 256, 0, stream>>>(bufB, W3, dinv, hs4);
    k_agg1<<<NNODES / 256, 256, 0, stream>>>(hs4, offs, csr_row, dinv, b3, cs);

    // sortpool + conv stack + lin1 + per-graph sum
    k_sub<<<NSUB, 128, 0, stream>>>(cs, c1w, c1b, c2w, c2b, l1w, l1b, gsum);
    // mean -> relu -> lin2 -> log_softmax
    k_head<<<64, 128, 0, stream>>>(gsum, l2w, l2b, out);
}

// Round 11
// 889.056 us; speedup vs baseline: 1.2921x; 1.0466x over previous
//
#include <hip/hip_runtime.h>
#include <math.h>

// Problem constants (fixed by reference setup_inputs)
#define NNODES 102400      // B*S*M = 64*32*50
#define NEDGES 3276800
#define FIN 256
#define DTOTC 97
#define KTOP 30
#define NSUB 2048          // B*S
#define MSZ 50
#define NRANGE 8           // node ranges (== XCD count heuristic)
#define RNODES (NNODES / NRANGE)    // 12800 nodes per range
#define NCHUNK 64          // edge chunks per range
#define CEDGES (NEDGES / NCHUNK)    // 51200 edges per chunk

// ---------------- CSR build: XCD-partitioned count + scatter ----------------
// block b: node range r = b&7 (maps to XCD r under round-robin dispatch -> all
// atomics/writes for a range stay in ONE XCD's L2), chunk = b>>3.
__global__ __launch_bounds__(256) void k_cnt_xcd(const int* __restrict__ col,
                                                 int* __restrict__ cnt) {
    int r = blockIdx.x & 7;
    int lo = r * RNODES, hi = lo + RNODES;
    int base = (blockIdx.x >> 3) * CEDGES;
#pragma unroll 2
    for (int it = 0; it < CEDGES / 1024; ++it) {
        int4 c = *(const int4*)&col[base + it * 1024 + threadIdx.x * 4];
        if (c.x >= lo && c.x < hi) atomicAdd(&cnt[c.x], 1);
        if (c.y >= lo && c.y < hi) atomicAdd(&cnt[c.y], 1);
        if (c.z >= lo && c.z < hi) atomicAdd(&cnt[c.z], 1);
        if (c.w >= lo && c.w < hi) atomicAdd(&cnt[c.w], 1);
    }
}

__global__ __launch_bounds__(256) void k_scatter_xcd(const int* __restrict__ ei,
                                                     const int* __restrict__ offs,
                                                     int* __restrict__ cursor,
                                                     int* __restrict__ csr_row) {
    int r = blockIdx.x & 7;
    int lo = r * RNODES, hi = lo + RNODES;
    int base = (blockIdx.x >> 3) * CEDGES;
    const int* rowp = ei;
    const int* colp = ei + NEDGES;
#pragma unroll 2
    for (int it = 0; it < CEDGES / 1024; ++it) {
        int e = base + it * 1024 + threadIdx.x * 4;
        int4 rr = *(const int4*)&rowp[e];
        int4 cc = *(const int4*)&colp[e];
        if (cc.x >= lo && cc.x < hi) csr_row[offs[cc.x] + atomicAdd(&cursor[cc.x], 1)] = rr.x;
        if (cc.y >= lo && cc.y < hi) csr_row[offs[cc.y] + atomicAdd(&cursor[cc.y], 1)] = rr.y;
        if (cc.z >= lo && cc.z < hi) csr_row[offs[cc.z] + atomicAdd(&cursor[cc.z], 1)] = rr.z;
        if (cc.w >= lo && cc.w < hi) csr_row[offs[cc.w] + atomicAdd(&cursor[cc.w], 1)] = rr.w;
    }
}

// ---------------- exclusive scan of per-node degrees (proven in round 1) ----------------
__global__ void k_scan1(const int* __restrict__ cnt, int* __restrict__ offs, int* __restrict__ aux) {
    __shared__ int s[256];
    int i = blockIdx.x * 256 + threadIdx.x;
    int v = (i < NNODES) ? cnt[i] : 0;
    s[threadIdx.x] = v;
    __syncthreads();
    for (int d = 1; d < 256; d <<= 1) {
        int t = (threadIdx.x >= d) ? s[threadIdx.x - d] : 0;
        __syncthreads();
        s[threadIdx.x] += t;
        __syncthreads();
    }
    if (i < NNODES) offs[i] = s[threadIdx.x] - v;   // exclusive within block
    if (threadIdx.x == 255) aux[blockIdx.x] = s[255];
}

__global__ void k_scan2(int* __restrict__ aux, int nb) {
    __shared__ int s[512];
    int t = threadIdx.x;
    int v = (t < nb) ? aux[t] : 0;
    s[t] = v;
    __syncthreads();
    for (int d = 1; d < 512; d <<= 1) {
        int x = (t >= d) ? s[t - d] : 0;
        __syncthreads();
        s[t] += x;
        __syncthreads();
    }
    if (t < nb) aux[t] = s[t] - v;                  // exclusive block offsets
}

__global__ void k_scan3(int* __restrict__ offs, const int* __restrict__ aux,
                        const int* __restrict__ cnt, float* __restrict__ dinv) {
    int i = blockIdx.x * 256 + threadIdx.x;
    if (i < NNODES) {
        offs[i] += aux[i >> 8];
        dinv[i] = 1.0f / sqrtf((float)(cnt[i] + 1));   // +1 self loop
    }
    if (i == 0) offs[NNODES] = NEDGES;
}

// ---------------- layer-0 GEMM: hs = (x @ W0) * dinv[row] ----------------
__global__ __launch_bounds__(256) void k_gemm256(const float* __restrict__ x,
                                                 const float* __restrict__ W,
                                                 const float* __restrict__ dinv,
                                                 float* __restrict__ hs) {
    __shared__ float Xs[32 * 256];   // 32 KB
    __shared__ float Ws[256 * 32];   // 32 KB, [k][col]
    int tid = threadIdx.x;
    int row0 = blockIdx.x * 32;
    const float4* Wv = (const float4*)W;
    const float4* Xv = (const float4*)(x + (size_t)row0 * 256);
    float4* Wsv = (float4*)Ws;
    float4* Xsv = (float4*)Xs;
    for (int i = tid; i < 2048; i += 256) {
        Wsv[i] = Wv[i];
        Xsv[i] = Xv[i];
    }
    __syncthreads();
    int colid = tid & 31;
    int rs = tid >> 5;
    float acc0 = 0.f, acc1 = 0.f, acc2 = 0.f, acc3 = 0.f;
    for (int k = 0; k < 256; k += 4) {
        float4 x0 = *(const float4*)&Xs[(rs) * 256 + k];
        float4 x1 = *(const float4*)&Xs[(rs + 8) * 256 + k];
        float4 x2 = *(const float4*)&Xs[(rs + 16) * 256 + k];
        float4 x3 = *(const float4*)&Xs[(rs + 24) * 256 + k];
        float w0 = Ws[(k + 0) * 32 + colid];
        float w1 = Ws[(k + 1) * 32 + colid];
        float w2 = Ws[(k + 2) * 32 + colid];
        float w3 = Ws[(k + 3) * 32 + colid];
        acc0 += x0.x * w0 + x0.y * w1 + x0.z * w2 + x0.w * w3;
        acc1 += x1.x * w0 + x1.y * w1 + x1.z * w2 + x1.w * w3;
        acc2 += x2.x * w0 + x2.y * w1 + x2.z * w2 + x2.w * w3;
        acc3 += x3.x * w0 + x3.y * w1 + x3.z * w2 + x3.w * w3;
    }
    hs[(size_t)(row0 + rs) * 32 + colid]      = acc0 * dinv[row0 + rs];
    hs[(size_t)(row0 + rs + 8) * 32 + colid]  = acc1 * dinv[row0 + rs + 8];
    hs[(size_t)(row0 + rs + 16) * 32 + colid] = acc2 * dinv[row0 + rs + 16];
    hs[(size_t)(row0 + rs + 24) * 32 + colid] = acc3 * dinv[row0 + rs + 24];
}

// ---------------- 32x32 GEMM: hs = (h @ W) * dinv[row] ----------------
__global__ __launch_bounds__(256) void k_gemm32(const float* __restrict__ h,
                                                const float* __restrict__ W,
                                                const float* __restrict__ dinv,
                                                float* __restrict__ hs) {
    __shared__ float Hs[64 * 32];
    __shared__ float Ws[32 * 32];
    int tid = threadIdx.x;
    int row0 = blockIdx.x * 64;
    const float4* Hv = (const float4*)(h + (size_t)row0 * 32);
    float4* Hsv = (float4*)Hs;
    for (int i = tid; i < 512; i += 256) Hsv[i] = Hv[i];
    for (int i = tid; i < 1024; i += 256) Ws[i] = W[i];
    __syncthreads();
    int colid = tid & 31;
    int rs = tid >> 5;
    for (int j = 0; j < 8; ++j) {
        int rl = rs * 8 + j;
        float acc = 0.f;
#pragma unroll
        for (int k = 0; k < 32; ++k) acc += Hs[rl * 32 + k] * Ws[k * 32 + colid];
        hs[(size_t)(row0 + rl) * 32 + colid] = acc * dinv[row0 + rl];
    }
}

// ---------------- aggregation (32 ch), software-pipelined 8-wide gather ----------------
__global__ __launch_bounds__(256) void k_agg32(const float* __restrict__ hs,
                                               const int* __restrict__ offs,
                                               const int* __restrict__ csr_row,
                                               const float* __restrict__ dinv,
                                               const float* __restrict__ bias,
                                               float* __restrict__ h_out,
                                               float* __restrict__ cs, int col_base) {
    int node = blockIdx.x * 8 + (threadIdx.x >> 5);
    int ch = threadIdx.x & 31;
    int s = offs[node], e = offs[node + 1];
    int cnt = e - s;
    float a0 = hs[(size_t)node * 32 + ch];   // self-loop (pre-scaled)
    float a1 = 0.f, a2 = 0.f, a3 = 0.f;
    int nfull = cnt >> 3;
    if (nfull > 0) {
        int idx[8];
#pragma unroll
        for (int j = 0; j < 8; ++j) idx[j] = csr_row[s + j];
        int p = s + 8;
        for (int b = 1; b < nfull; ++b, p += 8) {
            int nxt[8];
#pragma unroll
            for (int j = 0; j < 8; ++j) nxt[j] = csr_row[p + j];
            float v0 = hs[(size_t)idx[0] * 32 + ch];
            float v1 = hs[(size_t)idx[1] * 32 + ch];
            float v2 = hs[(size_t)idx[2] * 32 + ch];
            float v3 = hs[(size_t)idx[3] * 32 + ch];
            float v4 = hs[(size_t)idx[4] * 32 + ch];
            float v5 = hs[(size_t)idx[5] * 32 + ch];
            float v6 = hs[(size_t)idx[6] * 32 + ch];
            float v7 = hs[(size_t)idx[7] * 32 + ch];
            a0 += v0 + v4;
            a1 += v1 + v5;
            a2 += v2 + v6;
            a3 += v3 + v7;
#pragma unroll
            for (int j = 0; j < 8; ++j) idx[j] = nxt[j];
        }
        {
            float v0 = hs[(size_t)idx[0] * 32 + ch];
            float v1 = hs[(size_t)idx[1] * 32 + ch];
            float v2 = hs[(size_t)idx[2] * 32 + ch];
            float v3 = hs[(size_t)idx[3] * 32 + ch];
            float v4 = hs[(size_t)idx[4] * 32 + ch];
            float v5 = hs[(size_t)idx[5] * 32 + ch];
            float v6 = hs[(size_t)idx[6] * 32 + ch];
            float v7 = hs[(size_t)idx[7] * 32 + ch];
            a0 += v0 + v4;
            a1 += v1 + v5;
            a2 += v2 + v6;
            a3 += v3 + v7;
        }
    }
    for (int t = s + (nfull << 3); t < e; ++t) a0 += hs[(size_t)csr_row[t] * 32 + ch];
    float acc = (a0 + a1) + (a2 + a3);
    float v = tanhf(dinv[node] * acc + bias[ch]);
    h_out[(size_t)node * 32 + ch] = v;
    cs[(size_t)node * DTOTC + col_base + ch] = v;
}

// ---------------- layer-3 (32 -> 1) ----------------
__global__ void k_gemv1(const float* __restrict__ h, const float* __restrict__ W3,
                        const float* __restrict__ dinv, float* __restrict__ hs4) {
    int i = blockIdx.x * 256 + threadIdx.x;
    if (i >= NNODES) return;
    float acc = 0.f;
#pragma unroll
    for (int k = 0; k < 32; ++k) acc += h[(size_t)i * 32 + k] * W3[k];
    hs4[i] = acc * dinv[i];
}

__global__ void k_agg1(const float* __restrict__ hs4, const int* __restrict__ offs,
                       const int* __restrict__ csr_row, const float* __restrict__ dinv,
                       const float* __restrict__ b3, float* __restrict__ cs) {
    int node = blockIdx.x * 256 + threadIdx.x;
    if (node >= NNODES) return;
    int s = offs[node], e = offs[node + 1];
    float a0 = hs4[node], a1 = 0.f, a2 = 0.f, a3 = 0.f;
    int i = s;
    for (; i + 8 <= e; i += 8) {
        int idx[8];
#pragma unroll
        for (int j = 0; j < 8; ++j) idx[j] = csr_row[i + j];
        a0 += hs4[idx[0]] + hs4[idx[4]];
        a1 += hs4[idx[1]] + hs4[idx[5]];
        a2 += hs4[idx[2]] + hs4[idx[6]];
        a3 += hs4[idx[3]] + hs4[idx[7]];
    }
    for (; i < e; ++i) a0 += hs4[csr_row[i]];
    float acc = (a0 + a1) + (a2 + a3);
    cs[(size_t)node * DTOTC + 96] = tanhf(dinv[node] * acc + b3[0]);
}

// ---------------- fused sortpool -> conv1 -> maxpool -> conv2 -> lin1 -> graph sum ----------------
__global__ __launch_bounds__(128) void k_sub(const float* __restrict__ cs,
                                             const float* __restrict__ c1w, const float* __restrict__ c1b,
                                             const float* __restrict__ c2w, const float* __restrict__ c2b,
                                             const float* __restrict__ l1w, const float* __restrict__ l1b,
                                             float* __restrict__ gsum) {
    __shared__ float csb[MSZ * DTOTC];
    __shared__ float c1ws[16 * DTOTC];
    __shared__ float c2ws[32 * 16 * 5];
    __shared__ float h1s[16 * 30];
    __shared__ float m1s[16 * 15];
    __shared__ float h2s[352];
    __shared__ int ord[KTOP];
    int tid = threadIdx.x;
    int sub = blockIdx.x;
    const float* src = cs + (size_t)sub * (MSZ * DTOTC);
    for (int i = tid; i < MSZ * DTOTC; i += 128) csb[i] = src[i];
    for (int i = tid; i < 16 * DTOTC; i += 128) c1ws[i] = c1w[i];
    for (int i = tid; i < 32 * 16 * 5; i += 128) c2ws[i] = c2w[i];
    __syncthreads();
    if (tid < MSZ) {
        float v = csb[tid * DTOTC + 96];
        int rank = 0;
        for (int j = 0; j < MSZ; ++j) {
            float vj = csb[j * DTOTC + 96];
            rank += (vj > v) || (vj == v && j < tid);
        }
        if (rank < KTOP) ord[rank] = tid;
    }
    __syncthreads();
    for (int p = tid; p < 16 * 30; p += 128) {
        int o = p / 30, k = p % 30;
        const float* xr = &csb[ord[k] * DTOTC];
        const float* wr = &c1ws[o * DTOTC];
        float acc = c1b[o];
        for (int d = 0; d < DTOTC; ++d) acc += xr[d] * wr[d];
        h1s[o * 30 + k] = fmaxf(acc, 0.f);
    }
    __syncthreads();
    for (int p = tid; p < 16 * 15; p += 128) {
        int o = p / 15, j = p % 15;
        m1s[p] = fmaxf(h1s[o * 30 + 2 * j], h1s[o * 30 + 2 * j + 1]);
    }
    __syncthreads();
    for (int p = tid; p < 352; p += 128) {
        int o = p / 11, t = p % 11;
        float acc = c2b[o];
        for (int ic = 0; ic < 16; ++ic) {
#pragma unroll
            for (int j = 0; j < 5; ++j)
                acc += m1s[ic * 15 + t + j] * c2ws[(o * 16 + ic) * 5 + j];
        }
        h2s[p] = fmaxf(acc, 0.f);
    }
    __syncthreads();
    {
        int c = tid;
        float acc = l1b[c];
        for (int i = 0; i < 352; ++i) acc += h2s[i] * l1w[i * 128 + c];
        atomicAdd(&gsum[(sub >> 5) * 128 + c], acc);
    }
}

// ---------------- head: mean -> relu -> lin2 -> log_softmax ----------------
__global__ __launch_bounds__(128) void k_head(const float* __restrict__ gsum,
                                              const float* __restrict__ l2w,
                                              const float* __restrict__ l2b,
                                              float* __restrict__ out) {
    __shared__ float g[128];
    __shared__ float os[10];
    int b = blockIdx.x, tid = threadIdx.x;
    g[tid] = fmaxf(gsum[b * 128 + tid] * (1.0f / 32.0f), 0.f);
    __syncthreads();
    if (tid < 10) {
        float acc = l2b[tid];
        for (int k = 0; k < 128; ++k) acc += g[k] * l2w[k * 10 + tid];
        os[tid] = acc;
    }
    __syncthreads();
    if (tid == 0) {
        float m = os[0];
        for (int c = 1; c < 10; ++c) m = fmaxf(m, os[c]);
        float sum = 0.f;
        for (int c = 0; c < 10; ++c) sum += expf(os[c] - m);
        float l = m + logf(sum);
        for (int c = 0; c < 10; ++c) out[b * 10 + c] = os[c] - l;
    }
}

extern "C" void kernel_launch(void* const* d_in, const int* in_sizes, int n_in,
                              void* d_out, int out_size, void* d_ws, size_t ws_size,
                              hipStream_t stream) {
    const float* x   = (const float*)d_in[0];
    const int*   ei  = (const int*)d_in[1];
    const float* W0  = (const float*)d_in[2];
    const float* b0  = (const float*)d_in[3];
    const float* W1  = (const float*)d_in[4];
    const float* b1  = (const float*)d_in[5];
    const float* W2  = (const float*)d_in[6];
    const float* b2  = (const float*)d_in[7];
    const float* W3  = (const float*)d_in[8];
    const float* b3  = (const float*)d_in[9];
    const float* c1w = (const float*)d_in[10];
    const float* c1b = (const float*)d_in[11];
    const float* c2w = (const float*)d_in[12];
    const float* c2b = (const float*)d_in[13];
    const float* l1w = (const float*)d_in[14];
    const float* l1b = (const float*)d_in[15];
    const float* l2w = (const float*)d_in[16];
    const float* l2b = (const float*)d_in[17];
    float* out = (float*)d_out;

    char* ws = (char*)d_ws;
    size_t off = 0;
    auto alloc = [&](size_t bytes) {
        void* p = ws + off;
        off += (bytes + 255) & ~(size_t)255;
        return p;
    };
    int*   cnt     = (int*)alloc((NNODES + 1) * sizeof(int));
    int*   offs    = (int*)alloc((NNODES + 1) * sizeof(int));
    int*   cursor  = (int*)alloc((size_t)NNODES * sizeof(int));
    int*   aux     = (int*)alloc(512 * sizeof(int));
    float* dinv    = (float*)alloc((size_t)NNODES * sizeof(float));
    int*   csr_row = (int*)alloc((size_t)NEDGES * sizeof(int));
    float* bufA    = (float*)alloc((size_t)NNODES * 32 * sizeof(float));
    float* bufB    = (float*)alloc((size_t)NNODES * 32 * sizeof(float));
    float* cs      = (float*)alloc((size_t)NNODES * DTOTC * sizeof(float));
    float* hs4     = (float*)alloc((size_t)NNODES * sizeof(float));
    float* gsum    = (float*)alloc(64 * 128 * sizeof(float));

    hipMemsetAsync(cnt, 0, (NNODES + 1) * sizeof(int), stream);
    hipMemsetAsync(cursor, 0, (size_t)NNODES * sizeof(int), stream);
    hipMemsetAsync(gsum, 0, 64 * 128 * sizeof(float), stream);

    const int* col = ei + NEDGES;

    // CSR build: XCD-partitioned count -> scan -> XCD-partitioned scatter
    k_cnt_xcd<<<NRANGE * NCHUNK, 256, 0, stream>>>(col, cnt);
    k_scan1<<<NNODES / 256, 256, 0, stream>>>(cnt, offs, aux);
    k_scan2<<<1, 512, 0, stream>>>(aux, NNODES / 256);
    k_scan3<<<NNODES / 256, 256, 0, stream>>>(offs, aux, cnt, dinv);
    k_scatter_xcd<<<NRANGE * NCHUNK, 256, 0, stream>>>(ei, offs, cursor, csr_row);

    // layer 0: 256 -> 32
    k_gemm256<<<NNODES / 32, 256, 0, stream>>>(x, W0, dinv, bufA);
    k_agg32<<<NNODES / 8, 256, 0, stream>>>(bufA, offs, csr_row, dinv, b0, bufB, cs, 0);
    // layer 1: 32 -> 32
    k_gemm32<<<NNODES / 64, 256, 0, stream>>>(bufB, W1, dinv, bufA);
    k_agg32<<<NNODES / 8, 256, 0, stream>>>(bufA, offs, csr_row, dinv, b1, bufB, cs, 32);
    // layer 2: 32 -> 32
    k_gemm32<<<NNODES / 64, 256, 0, stream>>>(bufB, W2, dinv, bufA);
    k_agg32<<<NNODES / 8, 256, 0, stream>>>(bufA, offs, csr_row, dinv, b2, bufB, cs, 64);
    // layer 3: 32 -> 1
    k_gemv1<<<NNODES / 256, 256, 0, stream>>>(bufB, W3, dinv, hs4);
    k_agg1<<<NNODES / 256, 256, 0, stream>>>(hs4, offs, csr_row, dinv, b3, cs);

    // sortpool + conv stack + lin1 + per-graph sum
    k_sub<<<NSUB, 128, 0, stream>>>(cs, c1w, c1b, c2w, c2b, l1w, l1b, gsum);
    // mean -> relu -> lin2 -> log_softmax
    k_head<<<64, 128, 0, stream>>>(gsum, l2w, l2b, out);
}

// Round 13
// 867.203 us; speedup vs baseline: 1.3247x; 1.0252x over previous
//
#include <hip/hip_runtime.h>
#include <math.h>

// Problem constants (fixed by reference setup_inputs)
#define NNODES 102400      // B*S*M = 64*32*50
#define NEDGES 3276800
#define FIN 256
#define DTOTC 97
#define KTOP 30
#define NSUB 2048          // B*S
#define MSZ 50
#define NRANGE 8           // node ranges (== XCD count heuristic)
#define RNODES (NNODES / NRANGE)    // 12800 nodes per range
#define NCHUNK 200         // edge chunks per range (1600 blocks -> ~78% occupancy)
#define CEDGES (NEDGES / NCHUNK)    // 16384 edges per chunk

// ---------------- CSR build: XCD-partitioned count + scatter ----------------
// block b: node range r = b&7 (maps to XCD r under round-robin dispatch -> all
// atomics/writes for a range stay in ONE XCD's L2), chunk = b>>3.
// Edge list (26 MB) is L3-resident, so the 8x re-stream is cheap (round-11 PMC:
// FETCH 103 MB not 420 MB). Occupancy was the round-11 bottleneck (20%).
__global__ __launch_bounds__(256) void k_cnt_xcd(const int* __restrict__ col,
                                                 int* __restrict__ cnt) {
    int r = blockIdx.x & 7;
    int lo = r * RNODES, hi = lo + RNODES;
    int base = (blockIdx.x >> 3) * CEDGES;
#pragma unroll 2
    for (int it = 0; it < CEDGES / 1024; ++it) {    // 16 iters
        int4 c = *(const int4*)&col[base + it * 1024 + threadIdx.x * 4];
        if (c.x >= lo && c.x < hi) atomicAdd(&cnt[c.x], 1);
        if (c.y >= lo && c.y < hi) atomicAdd(&cnt[c.y], 1);
        if (c.z >= lo && c.z < hi) atomicAdd(&cnt[c.z], 1);
        if (c.w >= lo && c.w < hi) atomicAdd(&cnt[c.w], 1);
    }
}

__global__ __launch_bounds__(256) void k_scatter_xcd(const int* __restrict__ ei,
                                                     const int* __restrict__ offs,
                                                     int* __restrict__ cursor,
                                                     int* __restrict__ csr_row) {
    int r = blockIdx.x & 7;
    int lo = r * RNODES, hi = lo + RNODES;
    int base = (blockIdx.x >> 3) * CEDGES;
    const int* rowp = ei;
    const int* colp = ei + NEDGES;
#pragma unroll 2
    for (int it = 0; it < CEDGES / 1024; ++it) {    // 16 iters
        int e = base + it * 1024 + threadIdx.x * 4;
        int4 rr = *(const int4*)&rowp[e];
        int4 cc = *(const int4*)&colp[e];
        if (cc.x >= lo && cc.x < hi) csr_row[offs[cc.x] + atomicAdd(&cursor[cc.x], 1)] = rr.x;
        if (cc.y >= lo && cc.y < hi) csr_row[offs[cc.y] + atomicAdd(&cursor[cc.y], 1)] = rr.y;
        if (cc.z >= lo && cc.z < hi) csr_row[offs[cc.z] + atomicAdd(&cursor[cc.z], 1)] = rr.z;
        if (cc.w >= lo && cc.w < hi) csr_row[offs[cc.w] + atomicAdd(&cursor[cc.w], 1)] = rr.w;
    }
}

// ---------------- exclusive scan of per-node degrees (proven in round 1) ----------------
__global__ void k_scan1(const int* __restrict__ cnt, int* __restrict__ offs, int* __restrict__ aux) {
    __shared__ int s[256];
    int i = blockIdx.x * 256 + threadIdx.x;
    int v = (i < NNODES) ? cnt[i] : 0;
    s[threadIdx.x] = v;
    __syncthreads();
    for (int d = 1; d < 256; d <<= 1) {
        int t = (threadIdx.x >= d) ? s[threadIdx.x - d] : 0;
        __syncthreads();
        s[threadIdx.x] += t;
        __syncthreads();
    }
    if (i < NNODES) offs[i] = s[threadIdx.x] - v;   // exclusive within block
    if (threadIdx.x == 255) aux[blockIdx.x] = s[255];
}

__global__ void k_scan2(int* __restrict__ aux, int nb) {
    __shared__ int s[512];
    int t = threadIdx.x;
    int v = (t < nb) ? aux[t] : 0;
    s[t] = v;
    __syncthreads();
    for (int d = 1; d < 512; d <<= 1) {
        int x = (t >= d) ? s[t - d] : 0;
        __syncthreads();
        s[t] += x;
        __syncthreads();
    }
    if (t < nb) aux[t] = s[t] - v;                  // exclusive block offsets
}

__global__ void k_scan3(int* __restrict__ offs, const int* __restrict__ aux,
                        const int* __restrict__ cnt, float* __restrict__ dinv) {
    int i = blockIdx.x * 256 + threadIdx.x;
    if (i < NNODES) {
        offs[i] += aux[i >> 8];
        dinv[i] = 1.0f / sqrtf((float)(cnt[i] + 1));   // +1 self loop
    }
    if (i == 0) offs[NNODES] = NEDGES;
}

// ---------------- layer-0 GEMM: hs = (x @ W0) * dinv[row] ----------------
__global__ __launch_bounds__(256) void k_gemm256(const float* __restrict__ x,
                                                 const float* __restrict__ W,
                                                 const float* __restrict__ dinv,
                                                 float* __restrict__ hs) {
    __shared__ float Xs[32 * 256];   // 32 KB
    __shared__ float Ws[256 * 32];   // 32 KB, [k][col]
    int tid = threadIdx.x;
    int row0 = blockIdx.x * 32;
    const float4* Wv = (const float4*)W;
    const float4* Xv = (const float4*)(x + (size_t)row0 * 256);
    float4* Wsv = (float4*)Ws;
    float4* Xsv = (float4*)Xs;
    for (int i = tid; i < 2048; i += 256) {
        Wsv[i] = Wv[i];
        Xsv[i] = Xv[i];
    }
    __syncthreads();
    int colid = tid & 31;
    int rs = tid >> 5;
    float acc0 = 0.f, acc1 = 0.f, acc2 = 0.f, acc3 = 0.f;
    for (int k = 0; k < 256; k += 4) {
        float4 x0 = *(const float4*)&Xs[(rs) * 256 + k];
        float4 x1 = *(const float4*)&Xs[(rs + 8) * 256 + k];
        float4 x2 = *(const float4*)&Xs[(rs + 16) * 256 + k];
        float4 x3 = *(const float4*)&Xs[(rs + 24) * 256 + k];
        float w0 = Ws[(k + 0) * 32 + colid];
        float w1 = Ws[(k + 1) * 32 + colid];
        float w2 = Ws[(k + 2) * 32 + colid];
        float w3 = Ws[(k + 3) * 32 + colid];
        acc0 += x0.x * w0 + x0.y * w1 + x0.z * w2 + x0.w * w3;
        acc1 += x1.x * w0 + x1.y * w1 + x1.z * w2 + x1.w * w3;
        acc2 += x2.x * w0 + x2.y * w1 + x2.z * w2 + x2.w * w3;
        acc3 += x3.x * w0 + x3.y * w1 + x3.z * w2 + x3.w * w3;
    }
    hs[(size_t)(row0 + rs) * 32 + colid]      = acc0 * dinv[row0 + rs];
    hs[(size_t)(row0 + rs + 8) * 32 + colid]  = acc1 * dinv[row0 + rs + 8];
    hs[(size_t)(row0 + rs + 16) * 32 + colid] = acc2 * dinv[row0 + rs + 16];
    hs[(size_t)(row0 + rs + 24) * 32 + colid] = acc3 * dinv[row0 + rs + 24];
}

// ---------------- 32x32 GEMM: hs = (h @ W) * dinv[row] ----------------
__global__ __launch_bounds__(256) void k_gemm32(const float* __restrict__ h,
                                                const float* __restrict__ W,
                                                const float* __restrict__ dinv,
                                                float* __restrict__ hs) {
    __shared__ float Hs[64 * 32];
    __shared__ float Ws[32 * 32];
    int tid = threadIdx.x;
    int row0 = blockIdx.x * 64;
    const float4* Hv = (const float4*)(h + (size_t)row0 * 32);
    float4* Hsv = (float4*)Hs;
    for (int i = tid; i < 512; i += 256) Hsv[i] = Hv[i];
    for (int i = tid; i < 1024; i += 256) Ws[i] = W[i];
    __syncthreads();
    int colid = tid & 31;
    int rs = tid >> 5;
    for (int j = 0; j < 8; ++j) {
        int rl = rs * 8 + j;
        float acc = 0.f;
#pragma unroll
        for (int k = 0; k < 32; ++k) acc += Hs[rl * 32 + k] * Ws[k * 32 + colid];
        hs[(size_t)(row0 + rl) * 32 + colid] = acc * dinv[row0 + rl];
    }
}

// ---------------- aggregation (32 ch), software-pipelined 8-wide gather ----------------
__global__ __launch_bounds__(256) void k_agg32(const float* __restrict__ hs,
                                               const int* __restrict__ offs,
                                               const int* __restrict__ csr_row,
                                               const float* __restrict__ dinv,
                                               const float* __restrict__ bias,
                                               float* __restrict__ h_out,
                                               float* __restrict__ cs, int col_base) {
    int node = blockIdx.x * 8 + (threadIdx.x >> 5);
    int ch = threadIdx.x & 31;
    int s = offs[node], e = offs[node + 1];
    int cnt = e - s;
    float a0 = hs[(size_t)node * 32 + ch];   // self-loop (pre-scaled)
    float a1 = 0.f, a2 = 0.f, a3 = 0.f;
    int nfull = cnt >> 3;
    if (nfull > 0) {
        int idx[8];
#pragma unroll
        for (int j = 0; j < 8; ++j) idx[j] = csr_row[s + j];
        int p = s + 8;
        for (int b = 1; b < nfull; ++b, p += 8) {
            int nxt[8];
#pragma unroll
            for (int j = 0; j < 8; ++j) nxt[j] = csr_row[p + j];
            float v0 = hs[(size_t)idx[0] * 32 + ch];
            float v1 = hs[(size_t)idx[1] * 32 + ch];
            float v2 = hs[(size_t)idx[2] * 32 + ch];
            float v3 = hs[(size_t)idx[3] * 32 + ch];
            float v4 = hs[(size_t)idx[4] * 32 + ch];
            float v5 = hs[(size_t)idx[5] * 32 + ch];
            float v6 = hs[(size_t)idx[6] * 32 + ch];
            float v7 = hs[(size_t)idx[7] * 32 + ch];
            a0 += v0 + v4;
            a1 += v1 + v5;
            a2 += v2 + v6;
            a3 += v3 + v7;
#pragma unroll
            for (int j = 0; j < 8; ++j) idx[j] = nxt[j];
        }
        {
            float v0 = hs[(size_t)idx[0] * 32 + ch];
            float v1 = hs[(size_t)idx[1] * 32 + ch];
            float v2 = hs[(size_t)idx[2] * 32 + ch];
            float v3 = hs[(size_t)idx[3] * 32 + ch];
            float v4 = hs[(size_t)idx[4] * 32 + ch];
            float v5 = hs[(size_t)idx[5] * 32 + ch];
            float v6 = hs[(size_t)idx[6] * 32 + ch];
            float v7 = hs[(size_t)idx[7] * 32 + ch];
            a0 += v0 + v4;
            a1 += v1 + v5;
            a2 += v2 + v6;
            a3 += v3 + v7;
        }
    }
    for (int t = s + (nfull << 3); t < e; ++t) a0 += hs[(size_t)csr_row[t] * 32 + ch];
    float acc = (a0 + a1) + (a2 + a3);
    float v = tanhf(dinv[node] * acc + bias[ch]);
    h_out[(size_t)node * 32 + ch] = v;
    cs[(size_t)node * DTOTC + col_base + ch] = v;
}

// ---------------- layer-3 (32 -> 1) ----------------
__global__ void k_gemv1(const float* __restrict__ h, const float* __restrict__ W3,
                        const float* __restrict__ dinv, float* __restrict__ hs4) {
    int i = blockIdx.x * 256 + threadIdx.x;
    if (i >= NNODES) return;
    float acc = 0.f;
#pragma unroll
    for (int k = 0; k < 32; ++k) acc += h[(size_t)i * 32 + k] * W3[k];
    hs4[i] = acc * dinv[i];
}

__global__ void k_agg1(const float* __restrict__ hs4, const int* __restrict__ offs,
                       const int* __restrict__ csr_row, const float* __restrict__ dinv,
                       const float* __restrict__ b3, float* __restrict__ cs) {
    int node = blockIdx.x * 256 + threadIdx.x;
    if (node >= NNODES) return;
    int s = offs[node], e = offs[node + 1];
    float a0 = hs4[node], a1 = 0.f, a2 = 0.f, a3 = 0.f;
    int i = s;
    for (; i + 8 <= e; i += 8) {
        int idx[8];
#pragma unroll
        for (int j = 0; j < 8; ++j) idx[j] = csr_row[i + j];
        a0 += hs4[idx[0]] + hs4[idx[4]];
        a1 += hs4[idx[1]] + hs4[idx[5]];
        a2 += hs4[idx[2]] + hs4[idx[6]];
        a3 += hs4[idx[3]] + hs4[idx[7]];
    }
    for (; i < e; ++i) a0 += hs4[csr_row[i]];
    float acc = (a0 + a1) + (a2 + a3);
    cs[(size_t)node * DTOTC + 96] = tanhf(dinv[node] * acc + b3[0]);
}

// ---------------- fused sortpool -> conv1 -> maxpool -> conv2 -> lin1 -> graph sum ----------------
__global__ __launch_bounds__(128) void k_sub(const float* __restrict__ cs,
                                             const float* __restrict__ c1w, const float* __restrict__ c1b,
                                             const float* __restrict__ c2w, const float* __restrict__ c2b,
                                             const float* __restrict__ l1w, const float* __restrict__ l1b,
                                             float* __restrict__ gsum) {
    __shared__ float csb[MSZ * DTOTC];
    __shared__ float c1ws[16 * DTOTC];
    __shared__ float c2ws[32 * 16 * 5];
    __shared__ float h1s[16 * 30];
    __shared__ float m1s[16 * 15];
    __shared__ float h2s[352];
    __shared__ int ord[KTOP];
    int tid = threadIdx.x;
    int sub = blockIdx.x;
    const float* src = cs + (size_t)sub * (MSZ * DTOTC);
    for (int i = tid; i < MSZ * DTOTC; i += 128) csb[i] = src[i];
    for (int i = tid; i < 16 * DTOTC; i += 128) c1ws[i] = c1w[i];
    for (int i = tid; i < 32 * 16 * 5; i += 128) c2ws[i] = c2w[i];
    __syncthreads();
    if (tid < MSZ) {
        float v = csb[tid * DTOTC + 96];
        int rank = 0;
        for (int j = 0; j < MSZ; ++j) {
            float vj = csb[j * DTOTC + 96];
            rank += (vj > v) || (vj == v && j < tid);
        }
        if (rank < KTOP) ord[rank] = tid;
    }
    __syncthreads();
    for (int p = tid; p < 16 * 30; p += 128) {
        int o = p / 30, k = p % 30;
        const float* xr = &csb[ord[k] * DTOTC];
        const float* wr = &c1ws[o * DTOTC];
        float acc = c1b[o];
        for (int d = 0; d < DTOTC; ++d) acc += xr[d] * wr[d];
        h1s[o * 30 + k] = fmaxf(acc, 0.f);
    }
    __syncthreads();
    for (int p = tid; p < 16 * 15; p += 128) {
        int o = p / 15, j = p % 15;
        m1s[p] = fmaxf(h1s[o * 30 + 2 * j], h1s[o * 30 + 2 * j + 1]);
    }
    __syncthreads();
    for (int p = tid; p < 352; p += 128) {
        int o = p / 11, t = p % 11;
        float acc = c2b[o];
        for (int ic = 0; ic < 16; ++ic) {
#pragma unroll
            for (int j = 0; j < 5; ++j)
                acc += m1s[ic * 15 + t + j] * c2ws[(o * 16 + ic) * 5 + j];
        }
        h2s[p] = fmaxf(acc, 0.f);
    }
    __syncthreads();
    {
        int c = tid;
        float acc = l1b[c];
        for (int i = 0; i < 352; ++i) acc += h2s[i] * l1w[i * 128 + c];
        atomicAdd(&gsum[(sub >> 5) * 128 + c], acc);
    }
}

// ---------------- head: mean -> relu -> lin2 -> log_softmax ----------------
__global__ __launch_bounds__(128) void k_head(const float* __restrict__ gsum,
                                              const float* __restrict__ l2w,
                                              const float* __restrict__ l2b,
                                              float* __restrict__ out) {
    __shared__ float g[128];
    __shared__ float os[10];
    int b = blockIdx.x, tid = threadIdx.x;
    g[tid] = fmaxf(gsum[b * 128 + tid] * (1.0f / 32.0f), 0.f);
    __syncthreads();
    if (tid < 10) {
        float acc = l2b[tid];
        for (int k = 0; k < 128; ++k) acc += g[k] * l2w[k * 10 + tid];
        os[tid] = acc;
    }
    __syncthreads();
    if (tid == 0) {
        float m = os[0];
        for (int c = 1; c < 10; ++c) m = fmaxf(m, os[c]);
        float sum = 0.f;
        for (int c = 0; c < 10; ++c) sum += expf(os[c] - m);
        float l = m + logf(sum);
        for (int c = 0; c < 10; ++c) out[b * 10 + c] = os[c] - l;
    }
}

extern "C" void kernel_launch(void* const* d_in, const int* in_sizes, int n_in,
                              void* d_out, int out_size, void* d_ws, size_t ws_size,
                              hipStream_t stream) {
    const float* x   = (const float*)d_in[0];
    const int*   ei  = (const int*)d_in[1];
    const float* W0  = (const float*)d_in[2];
    const float* b0  = (const float*)d_in[3];
    const float* W1  = (const float*)d_in[4];
    const float* b1  = (const float*)d_in[5];
    const float* W2  = (const float*)d_in[6];
    const float* b2  = (const float*)d_in[7];
    const float* W3  = (const float*)d_in[8];
    const float* b3  = (const float*)d_in[9];
    const float* c1w = (const float*)d_in[10];
    const float* c1b = (const float*)d_in[11];
    const float* c2w = (const float*)d_in[12];
    const float* c2b = (const float*)d_in[13];
    const float* l1w = (const float*)d_in[14];
    const float* l1b = (const float*)d_in[15];
    const float* l2w = (const float*)d_in[16];
    const float* l2b = (const float*)d_in[17];
    float* out = (float*)d_out;

    char* ws = (char*)d_ws;
    size_t off = 0;
    auto alloc = [&](size_t bytes) {
        void* p = ws + off;
        off += (bytes + 255) & ~(size_t)255;
        return p;
    };
    int*   cnt     = (int*)alloc((NNODES + 1) * sizeof(int));
    int*   offs    = (int*)alloc((NNODES + 1) * sizeof(int));
    int*   cursor  = (int*)alloc((size_t)NNODES * sizeof(int));
    int*   aux     = (int*)alloc(512 * sizeof(int));
    float* dinv    = (float*)alloc((size_t)NNODES * sizeof(float));
    int*   csr_row = (int*)alloc((size_t)NEDGES * sizeof(int));
    float* bufA    = (float*)alloc((size_t)NNODES * 32 * sizeof(float));
    float* bufB    = (float*)alloc((size_t)NNODES * 32 * sizeof(float));
    float* cs      = (float*)alloc((size_t)NNODES * DTOTC * sizeof(float));
    float* hs4     = (float*)alloc((size_t)NNODES * sizeof(float));
    float* gsum    = (float*)alloc(64 * 128 * sizeof(float));

    hipMemsetAsync(cnt, 0, (NNODES + 1) * sizeof(int), stream);
    hipMemsetAsync(cursor, 0, (size_t)NNODES * sizeof(int), stream);
    hipMemsetAsync(gsum, 0, 64 * 128 * sizeof(float), stream);

    const int* col = ei + NEDGES;

    // CSR build: XCD-partitioned count -> scan -> XCD-partitioned scatter
    k_cnt_xcd<<<NRANGE * NCHUNK, 256, 0, stream>>>(col, cnt);
    k_scan1<<<NNODES / 256, 256, 0, stream>>>(cnt, offs, aux);
    k_scan2<<<1, 512, 0, stream>>>(aux, NNODES / 256);
    k_scan3<<<NNODES / 256, 256, 0, stream>>>(offs, aux, cnt, dinv);
    k_scatter_xcd<<<NRANGE * NCHUNK, 256, 0, stream>>>(ei, offs, cursor, csr_row);

    // layer 0: 256 -> 32
    k_gemm256<<<NNODES / 32, 256, 0, stream>>>(x, W0, dinv, bufA);
    k_agg32<<<NNODES / 8, 256, 0, stream>>>(bufA, offs, csr_row, dinv, b0, bufB, cs, 0);
    // layer 1: 32 -> 32
    k_gemm32<<<NNODES / 64, 256, 0, stream>>>(bufB, W1, dinv, bufA);
    k_agg32<<<NNODES / 8, 256, 0, stream>>>(bufA, offs, csr_row, dinv, b1, bufB, cs, 32);
    // layer 2: 32 -> 32
    k_gemm32<<<NNODES / 64, 256, 0, stream>>>(bufB, W2, dinv, bufA);
    k_agg32<<<NNODES / 8, 256, 0, stream>>>(bufA, offs, csr_row, dinv, b2, bufB, cs, 64);
    // layer 3: 32 -> 1
    k_gemv1<<<NNODES / 256, 256, 0, stream>>>(bufB, W3, dinv, hs4);
    k_agg1<<<NNODES / 256, 256, 0, stream>>>(hs4, offs, csr_row, dinv, b3, cs);

    // sortpool + conv stack + lin1 + per-graph sum
    k_sub<<<NSUB, 128, 0, stream>>>(cs, c1w, c1b, c2w, c2b, l1w, l1b, gsum);
    // mean -> relu -> lin2 -> log_softmax
    k_head<<<64, 128, 0, stream>>>(gsum, l2w, l2b, out);
}